// Round 3
// baseline (483.278 us; speedup 1.0000x reference)
//
#include <hip/hip_runtime.h>
#include <hip/hip_bf16.h>
#include <stdint.h>

#define HN 16      // heads
#define TT 2048    // seq len (T == S)
#define BBATCH 2
#define EE 1024
#define HD 64
#define MM 4096    // TT*BBATCH

// Q projection pre-scaled by 0.125*log2(e): exp2(q'.k) == exp(0.125*q.k).
#define SCALEQ 0.18033688011112042f

typedef __attribute__((ext_vector_type(8))) __bf16 bfrag;
typedef __attribute__((ext_vector_type(4))) float f32x4;
typedef __attribute__((ext_vector_type(4))) short s16x4;

struct alignas(8) B4 { __bf16 a0, a1, a2, a3; };

__device__ __forceinline__ void gll16(const void* g, void* lds) {
  __builtin_amdgcn_global_load_lds(
      (const __attribute__((address_space(1))) void*)g,
      (__attribute__((address_space(3))) void*)lds, 16, 0, 0);
}

__device__ __forceinline__ f32x4 mfma_bf16(bfrag a, bfrag b, f32x4 c) {
  return __builtin_amdgcn_mfma_f32_16x16x32_bf16(a, b, c, 0, 0, 0);
}

// ---- XOR-swizzled 64-elem-row LDS tiles (16B chunk c of row r at c^(r&7)) --
__device__ __forceinline__ const bfrag* fragp(const __bf16* base, int row, int e) {
  return (const bfrag*)(base + row * 64 + ((((e >> 3) ^ row) & 7) << 3));
}
__device__ __forceinline__ void stage8(const __bf16* grow0, int gstride,
                                       __bf16* tile, int r0, int lane) {
  const int rr = lane >> 3;
  const int cl = (lane & 7) ^ rr;
  gll16(grow0 + (size_t)(r0 + rr) * gstride + cl * 8, tile + r0 * 64);
}

// kept for attn/avg (measured net win there in r2)
__device__ __forceinline__ void barrier_fence() {
  __builtin_amdgcn_s_barrier();
  __builtin_amdgcn_sched_barrier(0);
}

// ---- manual grid barrier (requires ALL nb blocks co-resident) -----------
// counter zeroed by hipMemsetAsync each replay; release fence flushes the
// writer XCD's L2 to device scope (G16), acquire on exit.
__device__ __forceinline__ void grid_barrier(unsigned int* ctr, unsigned int nb) {
  __syncthreads();
  if (threadIdx.x == 0) {
    __threadfence();   // release: this block's writes visible device-wide
    unsigned int old = __hip_atomic_fetch_add(ctr, 1u, __ATOMIC_RELEASE,
                                              __HIP_MEMORY_SCOPE_AGENT);
    unsigned int target = old - (old % nb) + nb;
    while (__hip_atomic_load(ctr, __ATOMIC_ACQUIRE,
                             __HIP_MEMORY_SCOPE_AGENT) < target)
      __builtin_amdgcn_s_sleep(2);
    __threadfence();   // acquire side
  }
  __syncthreads();
}

// ---------------- GEMM core (r0 form, plain syncthreads): gemm_o only ----
template <int MT>
__device__ __forceinline__ void gemm2(const __bf16* __restrict__ X,
                                      const __bf16* __restrict__ W,
                                      const float* __restrict__ bias,
                                      void* __restrict__ out, int mode,
                                      float scale, int m0, int n0,
                                      __bf16* As0, __bf16* As1,
                                      __bf16* Bs0, __bf16* Bs1) {
  const int tid = threadIdx.x, lane = tid & 63, w = tid >> 6;
  const int wm = w >> 1, wn = w & 1;
  const int quad = lane >> 4, l16 = lane & 15;
  constexpr int FM = MT / 32;   // m-frags per wave

  auto stageAB = [&](int buf, int k0) {
    __bf16* A = buf ? As1 : As0;
    __bf16* B = buf ? Bs1 : Bs0;
    #pragma unroll
    for (int c = 0; c < FM; ++c)
      stage8(X + (size_t)m0 * EE + k0, EE, A, w * (MT / 4) + c * 8, lane);
    #pragma unroll
    for (int c = 0; c < 4; ++c)
      stage8(W + (size_t)n0 * EE + k0, EE, B, w * 32 + c * 8, lane);
  };

  stageAB(0, 0);

  f32x4 acc[FM][4] = {};

  for (int it = 0; it < EE / 64; ++it) {
    const int cur = it & 1;
    __syncthreads();                 // buf[cur] staged; prior reads done
    if (it + 1 < EE / 64) stageAB(1 - cur, (it + 1) * 64);

    const __bf16* A = cur ? As1 : As0;
    const __bf16* B = cur ? Bs1 : Bs0;
    #pragma unroll
    for (int ks = 0; ks < 2; ++ks) {
      bfrag a[FM], b[4];
      #pragma unroll
      for (int f = 0; f < FM; ++f)
        a[f] = *fragp(A, wm * (MT / 2) + f * 16 + l16, ks * 32 + quad * 8);
      #pragma unroll
      for (int f = 0; f < 4; ++f)
        b[f] = *fragp(B, wn * 64 + f * 16 + l16, ks * 32 + quad * 8);
      #pragma unroll
      for (int fm = 0; fm < FM; ++fm)
        #pragma unroll
        for (int fn = 0; fn < 4; ++fn)
          acc[fm][fn] = mfma_bf16(a[fm], b[fn], acc[fm][fn]);
    }
  }

  float bv[4];
  #pragma unroll
  for (int fn = 0; fn < 4; ++fn) bv[fn] = bias[n0 + wn * 64 + fn * 16 + l16];

  #pragma unroll
  for (int fm = 0; fm < FM; ++fm) {
    #pragma unroll
    for (int r = 0; r < 4; ++r) {
      const int gm = m0 + wm * (MT / 2) + fm * 16 + quad * 4 + r;
      #pragma unroll
      for (int fn = 0; fn < 4; ++fn) {
        const int gn = n0 + wn * 64 + fn * 16 + l16;
        const float v = (acc[fm][fn][r] + bv[fn]) * scale;
        if (mode == 0) {
          const int t = gm >> 1, bb = gm & 1, h = gn >> 6, d = gn & 63;
          ((__bf16*)out)[(((size_t)(bb * HN + h)) * TT + t) * HD + d] = (__bf16)v;
        } else if (mode == 2) {
          const int s = gm >> 1, bb = gm & 1, h = gn >> 6, d = gn & 63;
          ((__bf16*)out)[(((size_t)(bb * HN + h)) * HD + d) * TT + s] = (__bf16)v;
        } else {
          ((float*)out)[(size_t)gm * EE + gn] = v;
        }
      }
    }
  }
}

// ---------------- K1: cvt (all 7 tensors) + grid barrier + QKV GEMM -------
// grid 768 @ launch_bounds(256,4): VGPR capped 128 (m69-verified 4 waves/SIMD
// point) + 32KB LDS -> >=4 blocks/CU capacity -> all 768 co-resident, so the
// manual grid barrier is safe. GEMM phase is the m97 single-buffer structure
// (stage -> sync -> 32 MFMA -> sync) at 3 blocks/CU.
struct Fused1 {
  const float* src[7];   // q,k,v,Wq,Wk,Wv,Wo
  __bf16* dst[7];        // xq,xk,xv,wqb,wkb,wvb,wob
  const float* bias[3];  // bq,bk,bv
  __bf16* outp[3];       // qbuf,kbuf,vtbuf
  unsigned int* ctr;
};

__global__ __launch_bounds__(256, 4) void cvt_gemm_qkv(Fused1 a) {
  __shared__ __bf16 As[128 * 64];   // 16KB
  __shared__ __bf16 Bs[128 * 64];   // 16KB

  // ---- phase 1: fp32 -> bf16, whole grid, grid-stride per tensor
  {
    const int gtid = blockIdx.x * 256 + threadIdx.x;
    const int gstr = 768 * 256;
    for (int z = 0; z < 7; ++z) {
      const int n4 = (z < 3) ? (1 << 20) : (1 << 18);
      const float4* s = (const float4*)a.src[z];
      B4* d = (B4*)a.dst[z];
      for (int i = gtid; i < n4; i += gstr) {
        float4 v = s[i];
        B4 o = {(__bf16)v.x, (__bf16)v.y, (__bf16)v.z, (__bf16)v.w};
        d[i] = o;
      }
    }
  }

  grid_barrier(a.ctr, 768);

  // ---- phase 2: 128x128 tile single-buffer GEMM, 16 K-iterations
  const int tid = threadIdx.x, lane = tid & 63, w = tid >> 6;
  const int wm = w >> 1, wn = w & 1;
  const int quad = lane >> 4, l16 = lane & 15;

  // bx = m + 32*(n + 8*z): bx%8 == m%8 -> n-blocks sharing an A-tile on one XCD
  const int bx = blockIdx.x;
  const int m = bx & 31, n = (bx >> 5) & 7, z = bx >> 8;
  const __bf16 *X, *W;
  const float* bias;
  __bf16* out;
  int mode;
  float scale;
  if (z == 0)      { X = a.dst[0]; W = a.dst[3]; bias = a.bias[0]; out = a.outp[0]; mode = 0; scale = SCALEQ; }
  else if (z == 1) { X = a.dst[1]; W = a.dst[4]; bias = a.bias[1]; out = a.outp[1]; mode = 0; scale = 1.0f; }
  else             { X = a.dst[2]; W = a.dst[5]; bias = a.bias[2]; out = a.outp[2]; mode = 2; scale = 1.0f; }
  const int m0 = m * 128, n0 = n * 128;

  f32x4 acc[4][4] = {};

  for (int it = 0; it < 16; ++it) {
    const int k0 = it * 64;
    #pragma unroll
    for (int c = 0; c < 4; ++c)
      stage8(X + (size_t)m0 * EE + k0, EE, As, w * 32 + c * 8, lane);
    #pragma unroll
    for (int c = 0; c < 4; ++c)
      stage8(W + (size_t)n0 * EE + k0, EE, Bs, w * 32 + c * 8, lane);
    __syncthreads();   // implicit vmcnt(0): tile landed
    #pragma unroll
    for (int ks = 0; ks < 2; ++ks) {
      bfrag af[4], bf[4];
      #pragma unroll
      for (int f = 0; f < 4; ++f)
        af[f] = *fragp(As, wm * 64 + f * 16 + l16, ks * 32 + quad * 8);
      #pragma unroll
      for (int f = 0; f < 4; ++f)
        bf[f] = *fragp(Bs, wn * 64 + f * 16 + l16, ks * 32 + quad * 8);
      #pragma unroll
      for (int fm = 0; fm < 4; ++fm)
        #pragma unroll
        for (int fn = 0; fn < 4; ++fn)
          acc[fm][fn] = mfma_bf16(af[fm], bf[fn], acc[fm][fn]);
    }
    __syncthreads();   // reads done before next overwrite
  }

  float bvv[4];
  #pragma unroll
  for (int fn = 0; fn < 4; ++fn) bvv[fn] = bias[n0 + wn * 64 + fn * 16 + l16];

  #pragma unroll
  for (int fm = 0; fm < 4; ++fm) {
    #pragma unroll
    for (int r = 0; r < 4; ++r) {
      const int gm = m0 + wm * 64 + fm * 16 + quad * 4 + r;
      #pragma unroll
      for (int fn = 0; fn < 4; ++fn) {
        const int gn = n0 + wn * 64 + fn * 16 + l16;
        const float v = (acc[fm][fn][r] + bvv[fn]) * scale;
        if (mode == 0) {
          const int t = gm >> 1, bb = gm & 1, h = gn >> 6, d = gn & 63;
          out[(((size_t)(bb * HN + h)) * TT + t) * HD + d] = (__bf16)v;
        } else {
          const int s = gm >> 1, bb = gm & 1, h = gn >> 6, d = gn & 63;
          out[(((size_t)(bb * HN + h)) * HD + d) * TT + s] = (__bf16)v;
        }
      }
    }
  }
}

// ---------------- flash attention fwd body (r2 form, kept) ---------------
struct AttnSh {
  union { __bf16 kv[2][2][2][64 * 64]; float om[2][64 * 64]; } u;  // 64KB
  float Lsum[2][128];
  float LinvS[128];
};

__device__ void attn_body(const __bf16* __restrict__ qb,
                          const __bf16* __restrict__ kb,
                          const __bf16* __restrict__ vtb,
                          __bf16* __restrict__ ob,
                          float* __restrict__ linv_ws, int bx, AttnSh& sa) {
  const int tid = threadIdx.x, lane = tid & 63, w = tid >> 6;
  const int p = w >> 1, tw = w & 1;
  const int quad = lane >> 4, l16 = lane & 15;

  const int xcd = bx & 7, slot = bx >> 3;
  const int bhi = xcd * 4 + (slot >> 4);
  const int t0 = (slot & 15) * 128;
  const int b = bhi >> 4, h = bhi & 15;
  const size_t bh = (size_t)(b * HN + h);

  const __bf16* qbase = qb + (bh * TT + t0) * HD;
  const __bf16* kbase = kb + bh * TT * HD;
  const __bf16* vbase = vtb + bh * HD * TT;
  const int sBase = p * 1024;

  #pragma unroll
  for (int c = 0; c < 4; ++c) {
    stage8(kbase + (size_t)sBase * HD, HD, sa.u.kv[p][0][0], tw * 32 + c * 8, lane);
    stage8(vbase + sBase, TT, sa.u.kv[p][1][0], tw * 32 + c * 8, lane);
  }

  bfrag qf[4][2];
  #pragma unroll
  for (int fn = 0; fn < 4; ++fn)
    #pragma unroll
    for (int ks = 0; ks < 2; ++ks)
      qf[fn][ks] = *(const bfrag*)(qbase +
          (size_t)(tw * 64 + fn * 16 + l16) * HD + ks * 32 + quad * 8);

  bfrag ones;
  {
    union { short s[8]; bfrag v; } u;
    #pragma unroll
    for (int i = 0; i < 8; ++i) u.s[i] = 0x3F80;   // bf16 1.0
    ones = u.v;
  }

  f32x4 oacc[4][4] = {};   // [fm_d][fn_t] of O^T
  f32x4 lacc[4] = {};      // row sums via ones-MFMA

  for (int it = 0; it < 16; ++it) {
    const int cur = it & 1;
    barrier_fence();
    if (it + 1 < 16) {
      const int s1 = sBase + (it + 1) * 64;
      #pragma unroll
      for (int c = 0; c < 4; ++c) {
        stage8(kbase + (size_t)s1 * HD, HD, sa.u.kv[p][0][1 - cur], tw * 32 + c * 8, lane);
        stage8(vbase + s1, TT, sa.u.kv[p][1][1 - cur], tw * 32 + c * 8, lane);
      }
      asm volatile("s_waitcnt vmcnt(8)" ::: "memory");
    } else {
      asm volatile("s_waitcnt vmcnt(0)" ::: "memory");
    }
    barrier_fence();

    // ---- S^T[s][t] = K.Q
    f32x4 sacc[4][4] = {};
    #pragma unroll
    for (int ks = 0; ks < 2; ++ks) {
      bfrag kf[4];
      #pragma unroll
      for (int fm = 0; fm < 4; ++fm)
        kf[fm] = *fragp(sa.u.kv[p][0][cur], fm * 16 + l16, ks * 32 + quad * 8);
      #pragma unroll
      for (int fm = 0; fm < 4; ++fm)
        #pragma unroll
        for (int fn = 0; fn < 4; ++fn)
          sacc[fm][fn] = mfma_bf16(kf[fm], qf[fn][ks], sacc[fm][fn]);
    }

    // ---- exp2 in registers; pack into x32 B-operands
    union PB { __bf16 hh[8]; bfrag v; } pb[2][4];
    #pragma unroll
    for (int fm = 0; fm < 4; ++fm)
      #pragma unroll
      for (int fn = 0; fn < 4; ++fn) {
        const float p0 = __builtin_amdgcn_exp2f(sacc[fm][fn][0]);
        const float p1 = __builtin_amdgcn_exp2f(sacc[fm][fn][1]);
        const float p2 = __builtin_amdgcn_exp2f(sacc[fm][fn][2]);
        const float p3 = __builtin_amdgcn_exp2f(sacc[fm][fn][3]);
        const int hb = (fm & 1) * 4;
        pb[fm >> 1][fn].hh[hb + 0] = (__bf16)p0;
        pb[fm >> 1][fn].hh[hb + 1] = (__bf16)p1;
        pb[fm >> 1][fn].hh[hb + 2] = (__bf16)p2;
        pb[fm >> 1][fn].hh[hb + 3] = (__bf16)p3;
      }

    // ---- O^T += V^T.P^T ; l += 1.P^T on the MFMA pipe
    #pragma unroll
    for (int ks = 0; ks < 2; ++ks) {
      bfrag vf[4];
      #pragma unroll
      for (int fm = 0; fm < 4; ++fm) {
        const __bf16* base = sa.u.kv[p][1][cur] + (fm * 16 + l16) * 64;
        const int sw = l16 & 7, qh = quad >> 1, qo = (quad & 1) * 4;
        union VF { s16x4 q[2]; bfrag v; } u;
        u.q[0] = *(const s16x4*)(base + (((ks * 4 + qh) ^ sw) << 3) + qo);
        u.q[1] = *(const s16x4*)(base + (((ks * 4 + 2 + qh) ^ sw) << 3) + qo);
        vf[fm] = u.v;
      }
      #pragma unroll
      for (int fn = 0; fn < 4; ++fn)
        lacc[fn] = mfma_bf16(ones, pb[ks][fn].v, lacc[fn]);
      #pragma unroll
      for (int fm = 0; fm < 4; ++fm)
        #pragma unroll
        for (int fn = 0; fn < 4; ++fn)
          oacc[fm][fn] = mfma_bf16(vf[fm], pb[ks][fn].v, oacc[fm][fn]);
    }
  }

  if (quad == 0)
    #pragma unroll
    for (int fn = 0; fn < 4; ++fn)
      sa.Lsum[p][tw * 64 + fn * 16 + l16] = lacc[fn][0];

  __syncthreads();   // Lsum visible; K/V reads done -> om may alias

  if (p == 1) {
    #pragma unroll
    for (int fm = 0; fm < 4; ++fm)
      #pragma unroll
      for (int fn = 0; fn < 4; ++fn)
        #pragma unroll
        for (int r = 0; r < 4; ++r)
          sa.u.om[tw][(fm * 16 + quad * 4 + r) * 64 + fn * 16 + l16] = oacc[fm][fn][r];
  }
  if (tid < 128) {
    const float linv = 1.0f / (sa.Lsum[0][tid] + sa.Lsum[1][tid]);
    sa.LinvS[tid] = linv;
    linv_ws[bh * TT + t0 + tid] = linv;
  }
  __syncthreads();

  if (p == 0) {
    float li[4];
    #pragma unroll
    for (int fn = 0; fn < 4; ++fn) li[fn] = sa.LinvS[tw * 64 + fn * 16 + l16];
    #pragma unroll
    for (int fm = 0; fm < 4; ++fm)
      #pragma unroll
      for (int fn = 0; fn < 4; ++fn) {
        const int t = t0 + tw * 64 + fn * 16 + l16;
        B4 o;
        __bf16* op = &o.a0;
        #pragma unroll
        for (int r = 0; r < 4; ++r) {
          const float v = (oacc[fm][fn][r] +
              sa.u.om[tw][(fm * 16 + quad * 4 + r) * 64 + fn * 16 + l16]) * li[fn];
          op[r] = (__bf16)v;
        }
        *(B4*)(ob + ((size_t)t * BBATCH + b) * EE + h * HD + fm * 16 + quad * 4) = o;
      }
  }
}

// ---------------- avg_w body (r2 form, kept) -----------------------------
__device__ void avg_body(const __bf16* __restrict__ qb,
                         const __bf16* __restrict__ kb,
                         const float* __restrict__ linv_ws,
                         float* __restrict__ avg_out, int bx,
                         __bf16* Qs0, __bf16* Qs1,
                         __bf16* Ks0, __bf16* Ks1) {
  const int tid = threadIdx.x, lane = tid & 63, w = tid >> 6;
  const int wm = w >> 1, wn = w & 1;
  const int quad = lane >> 4, l16 = lane & 15;

  const int xcd = bx & 7, slot = bx >> 3;
  const int bti = xcd * 4 + (slot >> 4);
  const int s0 = (slot & 15) * 128;
  const int b = bti >> 4, t0 = (bti & 15) * 128;

  const __bf16* qt = qb + (((size_t)b * HN) * TT + t0) * HD;
  const __bf16* kt = kb + (((size_t)b * HN) * TT + s0) * HD;
  const float* lrow0 = linv_ws + ((size_t)b * HN) * TT + t0 + wm * 64;

  #pragma unroll
  for (int c = 0; c < 4; ++c) {
    stage8(qt, HD, Qs0, w * 32 + c * 8, lane);
    stage8(kt, HD, Ks0, w * 32 + c * 8, lane);
  }

  f32x4 aacc[4][4] = {};

  for (int h = 0; h < HN; ++h) {
    const int cur = h & 1;
    barrier_fence();
    if (h + 1 < HN) {
      const __bf16* qn = qt + (size_t)(h + 1) * TT * HD;
      const __bf16* kn = kt + (size_t)(h + 1) * TT * HD;
      __bf16* Qn = cur ? Qs0 : Qs1;
      __bf16* Kn = cur ? Ks0 : Ks1;
      #pragma unroll
      for (int c = 0; c < 4; ++c) {
        stage8(qn, HD, Qn, w * 32 + c * 8, lane);
        stage8(kn, HD, Kn, w * 32 + c * 8, lane);
      }
      asm volatile("s_waitcnt vmcnt(8)" ::: "memory");
    } else {
      asm volatile("s_waitcnt vmcnt(0)" ::: "memory");
    }
    barrier_fence();

    const __bf16* Qc = cur ? Qs1 : Qs0;
    const __bf16* Kc = cur ? Ks1 : Ks0;
    f32x4 sacc[4][4] = {};
    #pragma unroll
    for (int ks = 0; ks < 2; ++ks) {
      bfrag qf4[4], kf4[4];
      #pragma unroll
      for (int f = 0; f < 4; ++f)
        qf4[f] = *fragp(Qc, wm * 64 + f * 16 + l16, ks * 32 + quad * 8);
      #pragma unroll
      for (int f = 0; f < 4; ++f)
        kf4[f] = *fragp(Kc, wn * 64 + f * 16 + l16, ks * 32 + quad * 8);
      #pragma unroll
      for (int fm = 0; fm < 4; ++fm)
        #pragma unroll
        for (int fn = 0; fn < 4; ++fn)
          sacc[fm][fn] = mfma_bf16(qf4[fm], kf4[fn], sacc[fm][fn]);
    }

    const float* lr = lrow0 + (size_t)h * TT;
    f32x4 lvv[4];
    #pragma unroll
    for (int fm = 0; fm < 4; ++fm)
      lvv[fm] = *(const f32x4*)(lr + fm * 16 + quad * 4);

    #pragma unroll
    for (int fm = 0; fm < 4; ++fm)
      #pragma unroll
      for (int fn = 0; fn < 4; ++fn)
        #pragma unroll
        for (int r = 0; r < 4; ++r)
          aacc[fm][fn][r] += __builtin_amdgcn_exp2f(sacc[fm][fn][r]) * lvv[fm][r];
  }

  const float invh = 1.0f / (float)HN;
  #pragma unroll
  for (int fm = 0; fm < 4; ++fm)
    #pragma unroll
    for (int r = 0; r < 4; ++r) {
      const int t = t0 + wm * 64 + fm * 16 + quad * 4 + r;
      #pragma unroll
      for (int fn = 0; fn < 4; ++fn) {
        const int s = s0 + wn * 64 + fn * 16 + l16;
        avg_out[((size_t)b * TT + t) * TT + s] = aacc[fm][fn][r] * invh;
      }
    }
}

// ---------------- K2: attn + grid barrier + {avg, gemm_o} ----------------
// grid 512 @ (256,2): LDS union 67072 -> exactly 2 blocks/CU -> co-resident.
// After the barrier each block runs BOTH one avg unit and one gemm_o unit
// (order split at bx>=256 so a CU's two resident blocks run avg || gemm_o).
struct TailAvg { __bf16 Qs[2][128 * 64]; __bf16 Ks[2][128 * 64]; };  // 64KB
struct TailGo  { __bf16 As[2][64 * 64];  __bf16 Bs[2][128 * 64]; }; // 48KB
union Sh2 { AttnSh at; TailAvg a; TailGo g; };

__global__ __launch_bounds__(256, 2) void attn_tail(
    const __bf16* __restrict__ qb, const __bf16* __restrict__ kb,
    const __bf16* __restrict__ vtb, __bf16* __restrict__ ob,
    float* __restrict__ linv_ws, float* __restrict__ avg_out,
    const __bf16* __restrict__ wo, const float* __restrict__ bo,
    float* __restrict__ out, unsigned int* ctr) {
  __shared__ Sh2 sh;
  const int bx = blockIdx.x;

  attn_body(qb, kb, vtb, ob, linv_ws, bx, sh.at);

  grid_barrier(ctr, 512);

  const int gm_m = bx & 63, gm_n = bx >> 6;   // gemm_o unit = bx
  if ((bx >> 8) & 1) {
    gemm2<64>(ob, wo, bo, out, 3, 1.0f, gm_m * 64, gm_n * 128,
              sh.g.As[0], sh.g.As[1], sh.g.Bs[0], sh.g.Bs[1]);
    __syncthreads();
    avg_body(qb, kb, linv_ws, avg_out, bx,
             sh.a.Qs[0], sh.a.Qs[1], sh.a.Ks[0], sh.a.Ks[1]);
  } else {
    avg_body(qb, kb, linv_ws, avg_out, bx,
             sh.a.Qs[0], sh.a.Qs[1], sh.a.Ks[0], sh.a.Ks[1]);
    __syncthreads();
    gemm2<64>(ob, wo, bo, out, 3, 1.0f, gm_m * 64, gm_n * 128,
              sh.g.As[0], sh.g.As[1], sh.g.Bs[0], sh.g.Bs[1]);
  }
}

extern "C" void kernel_launch(void* const* d_in, const int* in_sizes, int n_in,
                              void* d_out, int out_size, void* d_ws, size_t ws_size,
                              hipStream_t stream) {
  (void)in_sizes; (void)n_in; (void)out_size; (void)ws_size;
  const float* query = (const float*)d_in[0];
  const float* key   = (const float*)d_in[1];
  const float* value = (const float*)d_in[2];
  const float* Wq = (const float*)d_in[3];
  const float* bq = (const float*)d_in[4];
  const float* Wk = (const float*)d_in[5];
  const float* bk = (const float*)d_in[6];
  const float* Wv = (const float*)d_in[7];
  const float* bv = (const float*)d_in[8];
  const float* Wo = (const float*)d_in[9];
  const float* bo = (const float*)d_in[10];

  char* ws = (char*)d_ws;
  size_t off = 0;
  auto wsalloc = [&](size_t bytes) -> void* {
    void* p = ws + off;
    off += (bytes + 255) & ~(size_t)255;
    return p;
  };
  const size_t XE = (size_t)MM * EE;
  const size_t WE = (size_t)EE * EE;
  __bf16* xq   = (__bf16*)wsalloc(XE * 2);
  __bf16* xk   = (__bf16*)wsalloc(XE * 2);
  __bf16* xv   = (__bf16*)wsalloc(XE * 2);
  __bf16* wqb  = (__bf16*)wsalloc(WE * 2);
  __bf16* wkb  = (__bf16*)wsalloc(WE * 2);
  __bf16* wvb  = (__bf16*)wsalloc(WE * 2);
  __bf16* wob  = (__bf16*)wsalloc(WE * 2);
  __bf16* qbuf = (__bf16*)wsalloc(XE * 2);
  __bf16* kbuf = (__bf16*)wsalloc(XE * 2);
  __bf16* vtbuf= (__bf16*)wsalloc(XE * 2);
  __bf16* obuf = (__bf16*)wsalloc(XE * 2);
  float* linv  = (float*)wsalloc((size_t)BBATCH * HN * TT * 4);
  unsigned int* ctrs = (unsigned int*)wsalloc(512);   // 2 counters, 256B apart

  hipMemsetAsync(ctrs, 0, 512, stream);

  Fused1 f1;
  f1.src[0] = query; f1.src[1] = key; f1.src[2] = value;
  f1.src[3] = Wq;    f1.src[4] = Wk;  f1.src[5] = Wv;  f1.src[6] = Wo;
  f1.dst[0] = xq;    f1.dst[1] = xk;  f1.dst[2] = xv;
  f1.dst[3] = wqb;   f1.dst[4] = wkb; f1.dst[5] = wvb; f1.dst[6] = wob;
  f1.bias[0] = bq;   f1.bias[1] = bk; f1.bias[2] = bv;
  f1.outp[0] = qbuf; f1.outp[1] = kbuf; f1.outp[2] = vtbuf;
  f1.ctr = ctrs;

  cvt_gemm_qkv<<<dim3(768), 256, 0, stream>>>(f1);

  float* avg_out = (float*)d_out + (size_t)TT * BBATCH * EE;
  attn_tail<<<dim3(512), 256, 0, stream>>>(qbuf, kbuf, vtbuf, obuf, linv,
                                           avg_out, wob, bo, (float*)d_out,
                                           ctrs + 64);
}

// Round 4
// 267.844 us; speedup vs baseline: 1.8043x; 1.8043x over previous
//
#include <hip/hip_runtime.h>
#include <hip/hip_bf16.h>
#include <stdint.h>

#define HN 16      // heads
#define TT 2048    // seq len (T == S)
#define BBATCH 2
#define EE 1024
#define HD 64
#define MM 4096    // TT*BBATCH

// Q projection pre-scaled by 0.125*log2(e): exp2(q'.k) == exp(0.125*q.k).
#define SCALEQ 0.18033688011112042f

typedef __attribute__((ext_vector_type(8))) __bf16 bfrag;
typedef __attribute__((ext_vector_type(4))) float f32x4;
typedef __attribute__((ext_vector_type(4))) short s16x4;

struct alignas(8) B4 { __bf16 a0, a1, a2, a3; };
struct alignas(16) B8 { __bf16 h[8]; };

__device__ __forceinline__ void gll16(const void* g, void* lds) {
  __builtin_amdgcn_global_load_lds(
      (const __attribute__((address_space(1))) void*)g,
      (__attribute__((address_space(3))) void*)lds, 16, 0, 0);
}

__device__ __forceinline__ f32x4 mfma_bf16(bfrag a, bfrag b, f32x4 c) {
  return __builtin_amdgcn_mfma_f32_16x16x32_bf16(a, b, c, 0, 0, 0);
}

// ---- XOR-swizzled 64-elem-row LDS tiles (16B chunk c of row r at c^(r&7)) --
__device__ __forceinline__ const bfrag* fragp(const __bf16* base, int row, int e) {
  return (const bfrag*)(base + row * 64 + ((((e >> 3) ^ row) & 7) << 3));
}
__device__ __forceinline__ void stage8(const __bf16* grow0, int gstride,
                                       __bf16* tile, int r0, int lane) {
  const int rr = lane >> 3;
  const int cl = (lane & 7) ^ rr;
  gll16(grow0 + (size_t)(r0 + rr) * gstride + cl * 8, tile + r0 * 64);
}

// counted-vmcnt barrier parts for attn/avg (measured win in r2)
__device__ __forceinline__ void barrier_fence() {
  __builtin_amdgcn_s_barrier();
  __builtin_amdgcn_sched_barrier(0);
}

// light barrier for pure-reg-staged loops: drains LDS ops only. VMEM loads
// headed to REGISTERS stay outstanding across the barrier (no gll16 here,
// so no vmcnt drain is ever needed for LDS consistency).
__device__ __forceinline__ void lbar() {
  __builtin_amdgcn_sched_barrier(0);
  asm volatile("s_waitcnt lgkmcnt(0)" ::: "memory");
  __builtin_amdgcn_s_barrier();
  __builtin_amdgcn_sched_barrier(0);
}

// ---------------- QKV GEMM with fused fp32->bf16 conversion --------------
// 128x128 tile, BK=64, dbuf. X and W are read as fp32 directly (the cvt
// kernel is gone): global fp32 -> regs -> cvt -> swizzled ds_write_b128.
// Loads for tile it+2 are issued at the end of iter it and consumed at the
// end of iter it+1 -> a full MFMA phase + 2 light barriers of latency
// hiding, with no vmcnt drain at the barrier at all.
// Per thread per tile: rows rA+32i (rA=tid>>3), 8-elem chunk cc=tid&7.
__global__ __launch_bounds__(256, 2) void gemm_qkv(
    const float* __restrict__ xq, const float* __restrict__ xk,
    const float* __restrict__ xv, const float* __restrict__ wq,
    const float* __restrict__ wk, const float* __restrict__ wv,
    const float* __restrict__ bq, const float* __restrict__ bk,
    const float* __restrict__ bv, __bf16* __restrict__ qo,
    __bf16* __restrict__ ko, __bf16* __restrict__ vo) {
  __shared__ __bf16 As[2][128 * 64];   // 32KB
  __shared__ __bf16 Bs[2][128 * 64];   // 32KB
  const int tid = threadIdx.x, lane = tid & 63, w = tid >> 6;
  const int wm = w >> 1, wn = w & 1;
  const int quad = lane >> 4, l16 = lane & 15;

  // bx = m + 32*(n + 8*z): bx%8 == m%8 -> n-blocks sharing an A-tile on one XCD
  const int bx = blockIdx.x;
  const int m = bx & 31, n = (bx >> 5) & 7, z = bx >> 8;
  const float *X, *W, *bias;
  __bf16* out;
  int mode;
  float scale;
  if (z == 0)      { X = xq; W = wq; bias = bq; out = qo; mode = 0; scale = SCALEQ; }
  else if (z == 1) { X = xk; W = wk; bias = bk; out = ko; mode = 0; scale = 1.0f; }
  else             { X = xv; W = wv; bias = bv; out = vo; mode = 2; scale = 1.0f; }
  const int m0 = m * 128, n0 = n * 128;
  const float* Xg = X + (size_t)m0 * EE;
  const float* Wg = W + (size_t)n0 * EE;

  const int rA = tid >> 3;   // base row; rows rA + 32*i
  const int cc = tid & 7;    // 8-elem chunk within the 64-wide row

  float4 vA[8], vB[8];

  auto loadT = [&](const float* src, int k0, float4* dst) {
    #pragma unroll
    for (int i = 0; i < 4; ++i) {
      const float* p = src + (size_t)(rA + 32 * i) * EE + k0 + cc * 8;
      dst[2 * i]     = *(const float4*)p;
      dst[2 * i + 1] = *(const float4*)(p + 4);
    }
  };
  auto writeT = [&](__bf16* tile, const float4* v) {
    #pragma unroll
    for (int i = 0; i < 4; ++i) {
      const int r = rA + 32 * i;
      B8 o;
      o.h[0] = (__bf16)v[2 * i].x;     o.h[1] = (__bf16)v[2 * i].y;
      o.h[2] = (__bf16)v[2 * i].z;     o.h[3] = (__bf16)v[2 * i].w;
      o.h[4] = (__bf16)v[2 * i + 1].x; o.h[5] = (__bf16)v[2 * i + 1].y;
      o.h[6] = (__bf16)v[2 * i + 1].z; o.h[7] = (__bf16)v[2 * i + 1].w;
      *(B8*)(tile + r * 64 + (((cc ^ r) & 7) << 3)) = o;
    }
  };

  // prologue: tile0 staged, tile1 loads in flight
  loadT(Xg, 0, vA);  loadT(Wg, 0, vB);
  writeT(As[0], vA); writeT(Bs[0], vB);
  loadT(Xg, 64, vA); loadT(Wg, 64, vB);

  f32x4 acc[4][4] = {};

  for (int it = 0; it < 16; ++it) {
    const int cur = it & 1;
    lbar();   // prev readers of buf[1-cur] done; buf[cur] ds_writes visible

    const __bf16* A = As[cur];
    const __bf16* B = Bs[cur];
    #pragma unroll
    for (int ks = 0; ks < 2; ++ks) {
      bfrag af[4], bf[4];
      #pragma unroll
      for (int f = 0; f < 4; ++f)
        af[f] = *fragp(A, wm * 64 + f * 16 + l16, ks * 32 + quad * 8);
      #pragma unroll
      for (int f = 0; f < 4; ++f)
        bf[f] = *fragp(B, wn * 64 + f * 16 + l16, ks * 32 + quad * 8);
      #pragma unroll
      for (int fm = 0; fm < 4; ++fm)
        #pragma unroll
        for (int fn = 0; fn < 4; ++fn)
          acc[fm][fn] = mfma_bf16(af[fm], bf[fn], acc[fm][fn]);
    }

    if (it + 1 < 16) {           // consume tile it+1 regs -> LDS
      writeT(As[1 - cur], vA);
      writeT(Bs[1 - cur], vB);
    }
    if (it + 2 < 16) {           // issue tile it+2 loads (stay in flight)
      loadT(Xg, (it + 2) * 64, vA);
      loadT(Wg, (it + 2) * 64, vB);
    }
  }

  float bvv[4];
  #pragma unroll
  for (int fn = 0; fn < 4; ++fn) bvv[fn] = bias[n0 + wn * 64 + fn * 16 + l16];

  #pragma unroll
  for (int fm = 0; fm < 4; ++fm) {
    #pragma unroll
    for (int r = 0; r < 4; ++r) {
      const int gm = m0 + wm * 64 + fm * 16 + quad * 4 + r;
      #pragma unroll
      for (int fn = 0; fn < 4; ++fn) {
        const int gn = n0 + wn * 64 + fn * 16 + l16;
        const float v = (acc[fm][fn][r] + bvv[fn]) * scale;
        if (mode == 0) {
          const int t = gm >> 1, bb = gm & 1, h = gn >> 6, d = gn & 63;
          out[(((size_t)(bb * HN + h)) * TT + t) * HD + d] = (__bf16)v;
        } else {
          const int s = gm >> 1, bb = gm & 1, h = gn >> 6, d = gn & 63;
          out[(((size_t)(bb * HN + h)) * HD + d) * TT + s] = (__bf16)v;
        }
      }
    }
  }
}

// ---------------- output GEMM: A=obuf bf16 (gll16), B=Wo fp32 (reg-staged)
// Barrier drains the 2 oldest VMEM ops (the A-tile gll16) via vmcnt(8),
// keeping the 8 W-loads for tile it+1 in flight.
__device__ __forceinline__ void gemm2o(const __bf16* __restrict__ X,
                                       const float* __restrict__ W,
                                       const float* __restrict__ bias,
                                       float* __restrict__ out,
                                       int m0, int n0,
                                       __bf16* As0, __bf16* As1,
                                       __bf16* Bs0, __bf16* Bs1) {
  const int tid = threadIdx.x, lane = tid & 63, w = tid >> 6;
  const int wm = w >> 1, wn = w & 1;
  const int quad = lane >> 4, l16 = lane & 15;
  const int rA = tid >> 3, cc = tid & 7;
  const float* Wg = W + (size_t)n0 * EE;

  float4 vB[8];
  auto loadB = [&](int k0) {
    #pragma unroll
    for (int i = 0; i < 4; ++i) {
      const float* p = Wg + (size_t)(rA + 32 * i) * EE + k0 + cc * 8;
      vB[2 * i]     = *(const float4*)p;
      vB[2 * i + 1] = *(const float4*)(p + 4);
    }
  };
  auto writeB = [&](__bf16* tile) {
    #pragma unroll
    for (int i = 0; i < 4; ++i) {
      const int r = rA + 32 * i;
      B8 o;
      o.h[0] = (__bf16)vB[2 * i].x;     o.h[1] = (__bf16)vB[2 * i].y;
      o.h[2] = (__bf16)vB[2 * i].z;     o.h[3] = (__bf16)vB[2 * i].w;
      o.h[4] = (__bf16)vB[2 * i + 1].x; o.h[5] = (__bf16)vB[2 * i + 1].y;
      o.h[6] = (__bf16)vB[2 * i + 1].z; o.h[7] = (__bf16)vB[2 * i + 1].w;
      *(B8*)(tile + r * 64 + (((cc ^ r) & 7) << 3)) = o;
    }
  };
  auto stageA = [&](__bf16* A, int k0) {
    #pragma unroll
    for (int c = 0; c < 2; ++c)
      stage8(X + (size_t)m0 * EE + k0, EE, A, w * 16 + c * 8, lane);
  };

  // prologue: A0 gll16; B0 staged via regs; B1 loads in flight
  stageA(As0, 0);
  loadB(0);
  writeB(Bs0);        // waits loadB(0); stageA(0) is older -> retires first
  loadB(64);

  f32x4 acc[2][4] = {};

  for (int it = 0; it < 16; ++it) {
    const int cur = it & 1;
    // drain the A-tile gll16 (oldest in FIFO); keep the 8 B-loads flying
    __builtin_amdgcn_sched_barrier(0);
    if (it == 15) asm volatile("s_waitcnt vmcnt(0) lgkmcnt(0)" ::: "memory");
    else          asm volatile("s_waitcnt vmcnt(8) lgkmcnt(0)" ::: "memory");
    __builtin_amdgcn_s_barrier();
    __builtin_amdgcn_sched_barrier(0);

    if (it + 1 < 16) stageA(cur ? As0 : As1, (it + 1) * 64);

    const __bf16* A = cur ? As1 : As0;
    const __bf16* B = cur ? Bs1 : Bs0;
    #pragma unroll
    for (int ks = 0; ks < 2; ++ks) {
      bfrag af[2], bf[4];
      #pragma unroll
      for (int f = 0; f < 2; ++f)
        af[f] = *fragp(A, wm * 32 + f * 16 + l16, ks * 32 + quad * 8);
      #pragma unroll
      for (int f = 0; f < 4; ++f)
        bf[f] = *fragp(B, wn * 64 + f * 16 + l16, ks * 32 + quad * 8);
      #pragma unroll
      for (int fm = 0; fm < 2; ++fm)
        #pragma unroll
        for (int fn = 0; fn < 4; ++fn)
          acc[fm][fn] = mfma_bf16(af[fm], bf[fn], acc[fm][fn]);
    }

    if (it + 1 < 16) writeB(cur ? Bs0 : Bs1);
    if (it + 2 < 16) loadB((it + 2) * 64);
  }

  float bvv[4];
  #pragma unroll
  for (int fn = 0; fn < 4; ++fn) bvv[fn] = bias[n0 + wn * 64 + fn * 16 + l16];

  #pragma unroll
  for (int fm = 0; fm < 2; ++fm) {
    #pragma unroll
    for (int r = 0; r < 4; ++r) {
      const int gm = m0 + wm * 32 + fm * 16 + quad * 4 + r;
      #pragma unroll
      for (int fn = 0; fn < 4; ++fn) {
        const int gn = n0 + wn * 64 + fn * 16 + l16;
        out[(size_t)gm * EE + gn] = acc[fm][fn][r] + bvv[fn];
      }
    }
  }
}

// ---------------- flash attention fwd: O (normalized) + linv (r2 form) ---
__global__ __launch_bounds__(256, 2) void attn_fwd(const __bf16* __restrict__ qb,
                                                   const __bf16* __restrict__ kb,
                                                   const __bf16* __restrict__ vtb,
                                                   __bf16* __restrict__ ob,
                                                   float* __restrict__ linv_ws) {
  union Sh {
    __bf16 kv[2][2][2][64 * 64];  // [pair][K=0/V=1][buf] 64KB
    float om[2][64 * 64];         // epilogue O-merge scratch (32KB, aliased)
  };
  __shared__ Sh sm;
  __shared__ float Lsum[2][128];
  __shared__ float LinvS[128];

  const int tid = threadIdx.x, lane = tid & 63, w = tid >> 6;
  const int p = w >> 1, tw = w & 1;
  const int quad = lane >> 4, l16 = lane & 15;

  const int bx = blockIdx.x;
  const int xcd = bx & 7, slot = bx >> 3;
  const int bhi = xcd * 4 + (slot >> 4);
  const int t0 = (slot & 15) * 128;
  const int b = bhi >> 4, h = bhi & 15;
  const size_t bh = (size_t)(b * HN + h);

  const __bf16* qbase = qb + (bh * TT + t0) * HD;
  const __bf16* kbase = kb + bh * TT * HD;
  const __bf16* vbase = vtb + bh * HD * TT;
  const int sBase = p * 1024;

  #pragma unroll
  for (int c = 0; c < 4; ++c) {
    stage8(kbase + (size_t)sBase * HD, HD, sm.kv[p][0][0], tw * 32 + c * 8, lane);
    stage8(vbase + sBase, TT, sm.kv[p][1][0], tw * 32 + c * 8, lane);
  }

  bfrag qf[4][2];
  #pragma unroll
  for (int fn = 0; fn < 4; ++fn)
    #pragma unroll
    for (int ks = 0; ks < 2; ++ks)
      qf[fn][ks] = *(const bfrag*)(qbase +
          (size_t)(tw * 64 + fn * 16 + l16) * HD + ks * 32 + quad * 8);

  bfrag ones;
  {
    union { short s[8]; bfrag v; } u;
    #pragma unroll
    for (int i = 0; i < 8; ++i) u.s[i] = 0x3F80;   // bf16 1.0
    ones = u.v;
  }

  f32x4 oacc[4][4] = {};   // [fm_d][fn_t] of O^T
  f32x4 lacc[4] = {};      // row sums via ones-MFMA

  for (int it = 0; it < 16; ++it) {
    const int cur = it & 1;
    barrier_fence();
    if (it + 1 < 16) {
      const int s1 = sBase + (it + 1) * 64;
      #pragma unroll
      for (int c = 0; c < 4; ++c) {
        stage8(kbase + (size_t)s1 * HD, HD, sm.kv[p][0][1 - cur], tw * 32 + c * 8, lane);
        stage8(vbase + s1, TT, sm.kv[p][1][1 - cur], tw * 32 + c * 8, lane);
      }
      asm volatile("s_waitcnt vmcnt(8)" ::: "memory");
    } else {
      asm volatile("s_waitcnt vmcnt(0)" ::: "memory");
    }
    barrier_fence();

    // ---- S^T[s][t] = K.Q
    f32x4 sacc[4][4] = {};
    #pragma unroll
    for (int ks = 0; ks < 2; ++ks) {
      bfrag kf[4];
      #pragma unroll
      for (int fm = 0; fm < 4; ++fm)
        kf[fm] = *fragp(sm.kv[p][0][cur], fm * 16 + l16, ks * 32 + quad * 8);
      #pragma unroll
      for (int fm = 0; fm < 4; ++fm)
        #pragma unroll
        for (int fn = 0; fn < 4; ++fn)
          sacc[fm][fn] = mfma_bf16(kf[fm], qf[fn][ks], sacc[fm][fn]);
    }

    // ---- exp2 in registers; pack into x32 B-operands
    union PB { __bf16 hh[8]; bfrag v; } pb[2][4];
    #pragma unroll
    for (int fm = 0; fm < 4; ++fm)
      #pragma unroll
      for (int fn = 0; fn < 4; ++fn) {
        const float p0 = __builtin_amdgcn_exp2f(sacc[fm][fn][0]);
        const float p1 = __builtin_amdgcn_exp2f(sacc[fm][fn][1]);
        const float p2 = __builtin_amdgcn_exp2f(sacc[fm][fn][2]);
        const float p3 = __builtin_amdgcn_exp2f(sacc[fm][fn][3]);
        const int hb = (fm & 1) * 4;
        pb[fm >> 1][fn].hh[hb + 0] = (__bf16)p0;
        pb[fm >> 1][fn].hh[hb + 1] = (__bf16)p1;
        pb[fm >> 1][fn].hh[hb + 2] = (__bf16)p2;
        pb[fm >> 1][fn].hh[hb + 3] = (__bf16)p3;
      }

    // ---- O^T += V^T.P^T ; l += 1.P^T on the MFMA pipe
    #pragma unroll
    for (int ks = 0; ks < 2; ++ks) {
      bfrag vf[4];
      #pragma unroll
      for (int fm = 0; fm < 4; ++fm) {
        const __bf16* base = sm.kv[p][1][cur] + (fm * 16 + l16) * 64;
        const int sw = l16 & 7, qh = quad >> 1, qo = (quad & 1) * 4;
        union VF { s16x4 q[2]; bfrag v; } u;
        u.q[0] = *(const s16x4*)(base + (((ks * 4 + qh) ^ sw) << 3) + qo);
        u.q[1] = *(const s16x4*)(base + (((ks * 4 + 2 + qh) ^ sw) << 3) + qo);
        vf[fm] = u.v;
      }
      #pragma unroll
      for (int fn = 0; fn < 4; ++fn)
        lacc[fn] = mfma_bf16(ones, pb[ks][fn].v, lacc[fn]);
      #pragma unroll
      for (int fm = 0; fm < 4; ++fm)
        #pragma unroll
        for (int fn = 0; fn < 4; ++fn)
          oacc[fm][fn] = mfma_bf16(vf[fm], pb[ks][fn].v, oacc[fm][fn]);
    }
  }

  if (quad == 0)
    #pragma unroll
    for (int fn = 0; fn < 4; ++fn)
      Lsum[p][tw * 64 + fn * 16 + l16] = lacc[fn][0];

  __syncthreads();   // Lsum visible; K/V reads done -> om may alias

  if (p == 1) {
    #pragma unroll
    for (int fm = 0; fm < 4; ++fm)
      #pragma unroll
      for (int fn = 0; fn < 4; ++fn)
        #pragma unroll
        for (int r = 0; r < 4; ++r)
          sm.om[tw][(fm * 16 + quad * 4 + r) * 64 + fn * 16 + l16] = oacc[fm][fn][r];
  }
  if (tid < 128) {
    const float linv = 1.0f / (Lsum[0][tid] + Lsum[1][tid]);
    LinvS[tid] = linv;
    linv_ws[bh * TT + t0 + tid] = linv;
  }
  __syncthreads();

  if (p == 0) {
    float li[4];
    #pragma unroll
    for (int fn = 0; fn < 4; ++fn) li[fn] = LinvS[tw * 64 + fn * 16 + l16];
    #pragma unroll
    for (int fm = 0; fm < 4; ++fm)
      #pragma unroll
      for (int fn = 0; fn < 4; ++fn) {
        const int t = t0 + tw * 64 + fn * 16 + l16;
        B4 o;
        __bf16* op = &o.a0;
        #pragma unroll
        for (int r = 0; r < 4; ++r) {
          const float v = (oacc[fm][fn][r] +
              sm.om[tw][(fm * 16 + quad * 4 + r) * 64 + fn * 16 + l16]) * li[fn];
          op[r] = (__bf16)v;
        }
        *(B4*)(ob + ((size_t)t * BBATCH + b) * EE + h * HD + fm * 16 + quad * 4) = o;
      }
  }
}

// ---------------- avg_w body (r2 form) -----------------------------------
__device__ void avg_body(const __bf16* __restrict__ qb,
                         const __bf16* __restrict__ kb,
                         const float* __restrict__ linv_ws,
                         float* __restrict__ avg_out, int bx,
                         __bf16* Qs0, __bf16* Qs1,
                         __bf16* Ks0, __bf16* Ks1) {
  const int tid = threadIdx.x, lane = tid & 63, w = tid >> 6;
  const int wm = w >> 1, wn = w & 1;
  const int quad = lane >> 4, l16 = lane & 15;

  const int xcd = bx & 7, slot = bx >> 3;
  const int bti = xcd * 4 + (slot >> 4);
  const int s0 = (slot & 15) * 128;
  const int b = bti >> 4, t0 = (bti & 15) * 128;

  const __bf16* qt = qb + (((size_t)b * HN) * TT + t0) * HD;
  const __bf16* kt = kb + (((size_t)b * HN) * TT + s0) * HD;
  const float* lrow0 = linv_ws + ((size_t)b * HN) * TT + t0 + wm * 64;

  #pragma unroll
  for (int c = 0; c < 4; ++c) {
    stage8(qt, HD, Qs0, w * 32 + c * 8, lane);
    stage8(kt, HD, Ks0, w * 32 + c * 8, lane);
  }

  f32x4 aacc[4][4] = {};

  for (int h = 0; h < HN; ++h) {
    const int cur = h & 1;
    barrier_fence();
    if (h + 1 < HN) {
      const __bf16* qn = qt + (size_t)(h + 1) * TT * HD;
      const __bf16* kn = kt + (size_t)(h + 1) * TT * HD;
      __bf16* Qn = cur ? Qs0 : Qs1;
      __bf16* Kn = cur ? Ks0 : Ks1;
      #pragma unroll
      for (int c = 0; c < 4; ++c) {
        stage8(qn, HD, Qn, w * 32 + c * 8, lane);
        stage8(kn, HD, Kn, w * 32 + c * 8, lane);
      }
      asm volatile("s_waitcnt vmcnt(8)" ::: "memory");
    } else {
      asm volatile("s_waitcnt vmcnt(0)" ::: "memory");
    }
    barrier_fence();

    const __bf16* Qc = cur ? Qs1 : Qs0;
    const __bf16* Kc = cur ? Ks1 : Ks0;
    f32x4 sacc[4][4] = {};
    #pragma unroll
    for (int ks = 0; ks < 2; ++ks) {
      bfrag qf4[4], kf4[4];
      #pragma unroll
      for (int f = 0; f < 4; ++f)
        qf4[f] = *fragp(Qc, wm * 64 + f * 16 + l16, ks * 32 + quad * 8);
      #pragma unroll
      for (int f = 0; f < 4; ++f)
        kf4[f] = *fragp(Kc, wn * 64 + f * 16 + l16, ks * 32 + quad * 8);
      #pragma unroll
      for (int fm = 0; fm < 4; ++fm)
        #pragma unroll
        for (int fn = 0; fn < 4; ++fn)
          sacc[fm][fn] = mfma_bf16(qf4[fm], kf4[fn], sacc[fm][fn]);
    }

    const float* lr = lrow0 + (size_t)h * TT;
    f32x4 lvv[4];
    #pragma unroll
    for (int fm = 0; fm < 4; ++fm)
      lvv[fm] = *(const f32x4*)(lr + fm * 16 + quad * 4);

    #pragma unroll
    for (int fm = 0; fm < 4; ++fm)
      #pragma unroll
      for (int fn = 0; fn < 4; ++fn)
        #pragma unroll
        for (int r = 0; r < 4; ++r)
          aacc[fm][fn][r] += __builtin_amdgcn_exp2f(sacc[fm][fn][r]) * lvv[fm][r];
  }

  const float invh = 1.0f / (float)HN;
  #pragma unroll
  for (int fm = 0; fm < 4; ++fm)
    #pragma unroll
    for (int r = 0; r < 4; ++r) {
      const int t = t0 + wm * 64 + fm * 16 + quad * 4 + r;
      #pragma unroll
      for (int fn = 0; fn < 4; ++fn) {
        const int s = s0 + wn * 64 + fn * 16 + l16;
        avg_out[((size_t)b * TT + t) * TT + s] = aacc[fm][fn][r] * invh;
      }
    }
}

// ---------------- tail: avg_attn (blocks 0..511) + gemm_o (512..1023) ----
struct TailAvg { __bf16 Qs[2][128 * 64]; __bf16 Ks[2][128 * 64]; };  // 64KB
struct TailGo  { __bf16 As[2][64 * 64];  __bf16 Bs[2][128 * 64]; }; // 48KB
union TailSh { TailAvg a; TailGo g; };

__global__ __launch_bounds__(256, 2) void tail_fused(
    const __bf16* __restrict__ qb, const __bf16* __restrict__ kb,
    const float* __restrict__ linv_ws, float* __restrict__ avg_out,
    const __bf16* __restrict__ ob, const float* __restrict__ wo,
    const float* __restrict__ bo, float* __restrict__ out) {
  __shared__ TailSh sh;
  const int bx = blockIdx.x;
  if (bx < 512) {
    avg_body(qb, kb, linv_ws, avg_out, bx,
             sh.a.Qs[0], sh.a.Qs[1], sh.a.Ks[0], sh.a.Ks[1]);
  } else {
    const int b2 = bx - 512;
    const int m = b2 & 63, n = b2 >> 6;
    gemm2o(ob, wo, bo, out, m * 64, n * 128,
           sh.g.As[0], sh.g.As[1], sh.g.Bs[0], sh.g.Bs[1]);
  }
}

extern "C" void kernel_launch(void* const* d_in, const int* in_sizes, int n_in,
                              void* d_out, int out_size, void* d_ws, size_t ws_size,
                              hipStream_t stream) {
  (void)in_sizes; (void)n_in; (void)out_size; (void)ws_size;
  const float* query = (const float*)d_in[0];
  const float* key   = (const float*)d_in[1];
  const float* value = (const float*)d_in[2];
  const float* Wq = (const float*)d_in[3];
  const float* bq = (const float*)d_in[4];
  const float* Wk = (const float*)d_in[5];
  const float* bk = (const float*)d_in[6];
  const float* Wv = (const float*)d_in[7];
  const float* bv = (const float*)d_in[8];
  const float* Wo = (const float*)d_in[9];
  const float* bo = (const float*)d_in[10];

  char* ws = (char*)d_ws;
  size_t off = 0;
  auto wsalloc = [&](size_t bytes) -> void* {
    void* p = ws + off;
    off += (bytes + 255) & ~(size_t)255;
    return p;
  };
  const size_t XE = (size_t)MM * EE;
  __bf16* qbuf = (__bf16*)wsalloc(XE * 2);
  __bf16* kbuf = (__bf16*)wsalloc(XE * 2);
  __bf16* vtbuf= (__bf16*)wsalloc(XE * 2);
  __bf16* obuf = (__bf16*)wsalloc(XE * 2);
  float* linv  = (float*)wsalloc((size_t)BBATCH * HN * TT * 4);

  gemm_qkv<<<dim3(768), 256, 0, stream>>>(query, key, value, Wq, Wk, Wv,
                                          bq, bk, bv, qbuf, kbuf, vtbuf);

  attn_fwd<<<dim3(512), 256, 0, stream>>>(qbuf, kbuf, vtbuf, obuf, linv);

  float* avg_out = (float*)d_out + (size_t)TT * BBATCH * EE;
  tail_fused<<<dim3(1024), 256, 0, stream>>>(qbuf, kbuf, linv, avg_out,
                                             obuf, Wo, bo, (float*)d_out);
}

// Round 5
// 246.414 us; speedup vs baseline: 1.9612x; 1.0870x over previous
//
#include <hip/hip_runtime.h>
#include <hip/hip_bf16.h>
#include <stdint.h>

#define HN 16      // heads
#define TT 2048    // seq len (T == S)
#define BBATCH 2
#define EE 1024
#define HD 64
#define MM 4096    // TT*BBATCH

// Q projection pre-scaled by 0.125*log2(e): exp2(q'.k) == exp(0.125*q.k).
#define SCALEQ 0.18033688011112042f

typedef __attribute__((ext_vector_type(8))) __bf16 bfrag;
typedef __attribute__((ext_vector_type(4))) float f32x4;
typedef __attribute__((ext_vector_type(4))) short s16x4;

struct alignas(8) B4 { __bf16 a0, a1, a2, a3; };
struct alignas(16) B8 { __bf16 h[8]; };

__device__ __forceinline__ void gll16(const void* g, void* lds) {
  __builtin_amdgcn_global_load_lds(
      (const __attribute__((address_space(1))) void*)g,
      (__attribute__((address_space(3))) void*)lds, 16, 0, 0);
}

__device__ __forceinline__ f32x4 mfma_bf16(bfrag a, bfrag b, f32x4 c) {
  return __builtin_amdgcn_mfma_f32_16x16x32_bf16(a, b, c, 0, 0, 0);
}

// ---- XOR-swizzled 64-elem-row LDS tiles (16B chunk c of row r at c^(r&7)) --
__device__ __forceinline__ const bfrag* fragp(const __bf16* base, int row, int e) {
  return (const bfrag*)(base + row * 64 + ((((e >> 3) ^ row) & 7) << 3));
}
__device__ __forceinline__ void stage8(const __bf16* grow0, int gstride,
                                       __bf16* tile, int r0, int lane) {
  const int rr = lane >> 3;
  const int cl = (lane & 7) ^ rr;
  gll16(grow0 + (size_t)(r0 + rr) * gstride + cl * 8, tile + r0 * 64);
}

// counted-vmcnt barrier parts (r2-measured win for attn/avg/tail-gemm)
__device__ __forceinline__ void barrier_fence() {
  __builtin_amdgcn_s_barrier();
  __builtin_amdgcn_sched_barrier(0);
}

// light barrier for pure-reg-staged loops: drains LDS ops only; VMEM loads
// headed to registers stay outstanding across it.
__device__ __forceinline__ void lbar() {
  __builtin_amdgcn_sched_barrier(0);
  asm volatile("s_waitcnt lgkmcnt(0)" ::: "memory");
  __builtin_amdgcn_s_barrier();
  __builtin_amdgcn_sched_barrier(0);
}

// ---------------- QKV GEMM with fused fp32->bf16 conversion (r4 body) ----
// Also converts Wo -> wob at entry (consumed two launches later; the kernel
// boundary is the ordering fence, so no barrier needed).
__global__ __launch_bounds__(256, 2) void gemm_qkv(
    const float* __restrict__ xq, const float* __restrict__ xk,
    const float* __restrict__ xv, const float* __restrict__ wq,
    const float* __restrict__ wk, const float* __restrict__ wv,
    const float* __restrict__ bq, const float* __restrict__ bk,
    const float* __restrict__ bv, __bf16* __restrict__ qo,
    __bf16* __restrict__ ko, __bf16* __restrict__ vo,
    const float* __restrict__ wo, __bf16* __restrict__ wob) {
  __shared__ __bf16 As[2][128 * 64];   // 32KB
  __shared__ __bf16 Bs[2][128 * 64];   // 32KB
  const int tid = threadIdx.x, lane = tid & 63, w = tid >> 6;
  const int wm = w >> 1, wn = w & 1;
  const int quad = lane >> 4, l16 = lane & 15;

  // ---- Wo fp32 -> bf16 (grid-stride over 256K float4 chunks)
  {
    const int gtid = blockIdx.x * 256 + tid;
    const float4* s = (const float4*)wo;
    B4* d = (B4*)wob;
    for (int i = gtid; i < (1 << 18); i += 768 * 256) {
      float4 v = s[i];
      B4 o = {(__bf16)v.x, (__bf16)v.y, (__bf16)v.z, (__bf16)v.w};
      d[i] = o;
    }
  }

  // bx = m + 32*(n + 8*z): bx%8 == m%8 -> n-blocks sharing an A-tile on one XCD
  const int bx = blockIdx.x;
  const int m = bx & 31, n = (bx >> 5) & 7, z = bx >> 8;
  const float *X, *W, *bias;
  __bf16* out;
  int mode;
  float scale;
  if (z == 0)      { X = xq; W = wq; bias = bq; out = qo; mode = 0; scale = SCALEQ; }
  else if (z == 1) { X = xk; W = wk; bias = bk; out = ko; mode = 0; scale = 1.0f; }
  else             { X = xv; W = wv; bias = bv; out = vo; mode = 2; scale = 1.0f; }
  const int m0 = m * 128, n0 = n * 128;
  const float* Xg = X + (size_t)m0 * EE;
  const float* Wg = W + (size_t)n0 * EE;

  const int rA = tid >> 3;   // base row; rows rA + 32*i
  const int cc = tid & 7;    // 8-elem chunk within the 64-wide row

  float4 vA[8], vB[8];

  auto loadT = [&](const float* src, int k0, float4* dst) {
    #pragma unroll
    for (int i = 0; i < 4; ++i) {
      const float* p = src + (size_t)(rA + 32 * i) * EE + k0 + cc * 8;
      dst[2 * i]     = *(const float4*)p;
      dst[2 * i + 1] = *(const float4*)(p + 4);
    }
  };
  auto writeT = [&](__bf16* tile, const float4* v) {
    #pragma unroll
    for (int i = 0; i < 4; ++i) {
      const int r = rA + 32 * i;
      B8 o;
      o.h[0] = (__bf16)v[2 * i].x;     o.h[1] = (__bf16)v[2 * i].y;
      o.h[2] = (__bf16)v[2 * i].z;     o.h[3] = (__bf16)v[2 * i].w;
      o.h[4] = (__bf16)v[2 * i + 1].x; o.h[5] = (__bf16)v[2 * i + 1].y;
      o.h[6] = (__bf16)v[2 * i + 1].z; o.h[7] = (__bf16)v[2 * i + 1].w;
      *(B8*)(tile + r * 64 + (((cc ^ r) & 7) << 3)) = o;
    }
  };

  // prologue: tile0 staged, tile1 loads in flight
  loadT(Xg, 0, vA);  loadT(Wg, 0, vB);
  writeT(As[0], vA); writeT(Bs[0], vB);
  loadT(Xg, 64, vA); loadT(Wg, 64, vB);

  f32x4 acc[4][4] = {};

  for (int it = 0; it < 16; ++it) {
    const int cur = it & 1;
    lbar();   // prev readers of buf[1-cur] done; buf[cur] ds_writes visible

    const __bf16* A = As[cur];
    const __bf16* B = Bs[cur];
    #pragma unroll
    for (int ks = 0; ks < 2; ++ks) {
      bfrag af[4], bf[4];
      #pragma unroll
      for (int f = 0; f < 4; ++f)
        af[f] = *fragp(A, wm * 64 + f * 16 + l16, ks * 32 + quad * 8);
      #pragma unroll
      for (int f = 0; f < 4; ++f)
        bf[f] = *fragp(B, wn * 64 + f * 16 + l16, ks * 32 + quad * 8);
      #pragma unroll
      for (int fm = 0; fm < 4; ++fm)
        #pragma unroll
        for (int fn = 0; fn < 4; ++fn)
          acc[fm][fn] = mfma_bf16(af[fm], bf[fn], acc[fm][fn]);
    }

    if (it + 1 < 16) {           // consume tile it+1 regs -> LDS
      writeT(As[1 - cur], vA);
      writeT(Bs[1 - cur], vB);
    }
    if (it + 2 < 16) {           // issue tile it+2 loads (stay in flight)
      loadT(Xg, (it + 2) * 64, vA);
      loadT(Wg, (it + 2) * 64, vB);
    }
  }

  float bvv[4];
  #pragma unroll
  for (int fn = 0; fn < 4; ++fn) bvv[fn] = bias[n0 + wn * 64 + fn * 16 + l16];

  #pragma unroll
  for (int fm = 0; fm < 4; ++fm) {
    #pragma unroll
    for (int r = 0; r < 4; ++r) {
      const int gm = m0 + wm * 64 + fm * 16 + quad * 4 + r;
      #pragma unroll
      for (int fn = 0; fn < 4; ++fn) {
        const int gn = n0 + wn * 64 + fn * 16 + l16;
        const float v = (acc[fm][fn][r] + bvv[fn]) * scale;
        if (mode == 0) {
          const int t = gm >> 1, bb = gm & 1, h = gn >> 6, d = gn & 63;
          out[(((size_t)(bb * HN + h)) * TT + t) * HD + d] = (__bf16)v;
        } else {
          const int s = gm >> 1, bb = gm & 1, h = gn >> 6, d = gn & 63;
          out[(((size_t)(bb * HN + h)) * HD + d) * TT + s] = (__bf16)v;
        }
      }
    }
  }
}

// ---------------- GEMM core (r2 counted-vmcnt form): tail gemm_o ---------
template <int MT>
__device__ __forceinline__ void gemm2(const __bf16* __restrict__ X,
                                      const __bf16* __restrict__ W,
                                      const float* __restrict__ bias,
                                      float* __restrict__ out,
                                      int m0, int n0,
                                      __bf16* As0, __bf16* As1,
                                      __bf16* Bs0, __bf16* Bs1) {
  const int tid = threadIdx.x, lane = tid & 63, w = tid >> 6;
  const int wm = w >> 1, wn = w & 1;
  const int quad = lane >> 4, l16 = lane & 15;
  constexpr int FM = MT / 32;   // m-frags per wave
  constexpr int NLD = FM + 4;   // gll16 per thread per stage

  auto stageAB = [&](int buf, int k0) {
    __bf16* A = buf ? As1 : As0;
    __bf16* B = buf ? Bs1 : Bs0;
    #pragma unroll
    for (int c = 0; c < FM; ++c)
      stage8(X + (size_t)m0 * EE + k0, EE, A, w * (MT / 4) + c * 8, lane);
    #pragma unroll
    for (int c = 0; c < 4; ++c)
      stage8(W + (size_t)n0 * EE + k0, EE, B, w * 32 + c * 8, lane);
  };

  stageAB(0, 0);

  f32x4 acc[FM][4] = {};

  for (int it = 0; it < EE / 64; ++it) {
    const int cur = it & 1;
    barrier_fence();                       // readers of buf[1-cur] done
    if (it + 1 < EE / 64) {
      stageAB(1 - cur, (it + 1) * 64);     // next tile: stays in flight
      asm volatile("s_waitcnt vmcnt(%0)" :: "n"(NLD) : "memory");
    } else {
      asm volatile("s_waitcnt vmcnt(0)" ::: "memory");
    }
    barrier_fence();                       // all waves' cur-tile writes landed

    const __bf16* A = cur ? As1 : As0;
    const __bf16* B = cur ? Bs1 : Bs0;
    #pragma unroll
    for (int ks = 0; ks < 2; ++ks) {
      bfrag a[FM], b[4];
      #pragma unroll
      for (int f = 0; f < FM; ++f)
        a[f] = *fragp(A, wm * (MT / 2) + f * 16 + l16, ks * 32 + quad * 8);
      #pragma unroll
      for (int f = 0; f < 4; ++f)
        b[f] = *fragp(B, wn * 64 + f * 16 + l16, ks * 32 + quad * 8);
      #pragma unroll
      for (int fm = 0; fm < FM; ++fm)
        #pragma unroll
        for (int fn = 0; fn < 4; ++fn)
          acc[fm][fn] = mfma_bf16(a[fm], b[fn], acc[fm][fn]);
    }
  }

  float bv[4];
  #pragma unroll
  for (int fn = 0; fn < 4; ++fn) bv[fn] = bias[n0 + wn * 64 + fn * 16 + l16];

  #pragma unroll
  for (int fm = 0; fm < FM; ++fm) {
    #pragma unroll
    for (int r = 0; r < 4; ++r) {
      const int gm = m0 + wm * (MT / 2) + fm * 16 + quad * 4 + r;
      #pragma unroll
      for (int fn = 0; fn < 4; ++fn) {
        const int gn = n0 + wn * 64 + fn * 16 + l16;
        out[(size_t)gm * EE + gn] = acc[fm][fn][r] + bv[fn];
      }
    }
  }
}

// ---------------- flash attention fwd: O (normalized) + linv (r2 form) ---
__global__ __launch_bounds__(256, 2) void attn_fwd(const __bf16* __restrict__ qb,
                                                   const __bf16* __restrict__ kb,
                                                   const __bf16* __restrict__ vtb,
                                                   __bf16* __restrict__ ob,
                                                   float* __restrict__ linv_ws) {
  union Sh {
    __bf16 kv[2][2][2][64 * 64];  // [pair][K=0/V=1][buf] 64KB
    float om[2][64 * 64];         // epilogue O-merge scratch (32KB, aliased)
  };
  __shared__ Sh sm;
  __shared__ float Lsum[2][128];
  __shared__ float LinvS[128];

  const int tid = threadIdx.x, lane = tid & 63, w = tid >> 6;
  const int p = w >> 1, tw = w & 1;
  const int quad = lane >> 4, l16 = lane & 15;

  const int bx = blockIdx.x;
  const int xcd = bx & 7, slot = bx >> 3;
  const int bhi = xcd * 4 + (slot >> 4);
  const int t0 = (slot & 15) * 128;
  const int b = bhi >> 4, h = bhi & 15;
  const size_t bh = (size_t)(b * HN + h);

  const __bf16* qbase = qb + (bh * TT + t0) * HD;
  const __bf16* kbase = kb + bh * TT * HD;
  const __bf16* vbase = vtb + bh * HD * TT;
  const int sBase = p * 1024;

  #pragma unroll
  for (int c = 0; c < 4; ++c) {
    stage8(kbase + (size_t)sBase * HD, HD, sm.kv[p][0][0], tw * 32 + c * 8, lane);
    stage8(vbase + sBase, TT, sm.kv[p][1][0], tw * 32 + c * 8, lane);
  }

  bfrag qf[4][2];
  #pragma unroll
  for (int fn = 0; fn < 4; ++fn)
    #pragma unroll
    for (int ks = 0; ks < 2; ++ks)
      qf[fn][ks] = *(const bfrag*)(qbase +
          (size_t)(tw * 64 + fn * 16 + l16) * HD + ks * 32 + quad * 8);

  bfrag ones;
  {
    union { short s[8]; bfrag v; } u;
    #pragma unroll
    for (int i = 0; i < 8; ++i) u.s[i] = 0x3F80;   // bf16 1.0
    ones = u.v;
  }

  f32x4 oacc[4][4] = {};   // [fm_d][fn_t] of O^T
  f32x4 lacc[4] = {};      // row sums via ones-MFMA

  for (int it = 0; it < 16; ++it) {
    const int cur = it & 1;
    barrier_fence();
    if (it + 1 < 16) {
      const int s1 = sBase + (it + 1) * 64;
      #pragma unroll
      for (int c = 0; c < 4; ++c) {
        stage8(kbase + (size_t)s1 * HD, HD, sm.kv[p][0][1 - cur], tw * 32 + c * 8, lane);
        stage8(vbase + s1, TT, sm.kv[p][1][1 - cur], tw * 32 + c * 8, lane);
      }
      asm volatile("s_waitcnt vmcnt(8)" ::: "memory");
    } else {
      asm volatile("s_waitcnt vmcnt(0)" ::: "memory");
    }
    barrier_fence();

    // ---- S^T[s][t] = K.Q
    f32x4 sacc[4][4] = {};
    #pragma unroll
    for (int ks = 0; ks < 2; ++ks) {
      bfrag kf[4];
      #pragma unroll
      for (int fm = 0; fm < 4; ++fm)
        kf[fm] = *fragp(sm.kv[p][0][cur], fm * 16 + l16, ks * 32 + quad * 8);
      #pragma unroll
      for (int fm = 0; fm < 4; ++fm)
        #pragma unroll
        for (int fn = 0; fn < 4; ++fn)
          sacc[fm][fn] = mfma_bf16(kf[fm], qf[fn][ks], sacc[fm][fn]);
    }

    // ---- exp2 in registers; pack into x32 B-operands
    union PB { __bf16 hh[8]; bfrag v; } pb[2][4];
    #pragma unroll
    for (int fm = 0; fm < 4; ++fm)
      #pragma unroll
      for (int fn = 0; fn < 4; ++fn) {
        const float p0 = __builtin_amdgcn_exp2f(sacc[fm][fn][0]);
        const float p1 = __builtin_amdgcn_exp2f(sacc[fm][fn][1]);
        const float p2 = __builtin_amdgcn_exp2f(sacc[fm][fn][2]);
        const float p3 = __builtin_amdgcn_exp2f(sacc[fm][fn][3]);
        const int hb = (fm & 1) * 4;
        pb[fm >> 1][fn].hh[hb + 0] = (__bf16)p0;
        pb[fm >> 1][fn].hh[hb + 1] = (__bf16)p1;
        pb[fm >> 1][fn].hh[hb + 2] = (__bf16)p2;
        pb[fm >> 1][fn].hh[hb + 3] = (__bf16)p3;
      }

    // ---- O^T += V^T.P^T ; l += 1.P^T on the MFMA pipe
    #pragma unroll
    for (int ks = 0; ks < 2; ++ks) {
      bfrag vf[4];
      #pragma unroll
      for (int fm = 0; fm < 4; ++fm) {
        const __bf16* base = sm.kv[p][1][cur] + (fm * 16 + l16) * 64;
        const int sw = l16 & 7, qh = quad >> 1, qo = (quad & 1) * 4;
        union VF { s16x4 q[2]; bfrag v; } u;
        u.q[0] = *(const s16x4*)(base + (((ks * 4 + qh) ^ sw) << 3) + qo);
        u.q[1] = *(const s16x4*)(base + (((ks * 4 + 2 + qh) ^ sw) << 3) + qo);
        vf[fm] = u.v;
      }
      #pragma unroll
      for (int fn = 0; fn < 4; ++fn)
        lacc[fn] = mfma_bf16(ones, pb[ks][fn].v, lacc[fn]);
      #pragma unroll
      for (int fm = 0; fm < 4; ++fm)
        #pragma unroll
        for (int fn = 0; fn < 4; ++fn)
          oacc[fm][fn] = mfma_bf16(vf[fm], pb[ks][fn].v, oacc[fm][fn]);
    }
  }

  if (quad == 0)
    #pragma unroll
    for (int fn = 0; fn < 4; ++fn)
      Lsum[p][tw * 64 + fn * 16 + l16] = lacc[fn][0];

  __syncthreads();   // Lsum visible; K/V reads done -> om may alias

  if (p == 1) {
    #pragma unroll
    for (int fm = 0; fm < 4; ++fm)
      #pragma unroll
      for (int fn = 0; fn < 4; ++fn)
        #pragma unroll
        for (int r = 0; r < 4; ++r)
          sm.om[tw][(fm * 16 + quad * 4 + r) * 64 + fn * 16 + l16] = oacc[fm][fn][r];
  }
  if (tid < 128) {
    const float linv = 1.0f / (Lsum[0][tid] + Lsum[1][tid]);
    LinvS[tid] = linv;
    linv_ws[bh * TT + t0 + tid] = linv;
  }
  __syncthreads();

  if (p == 0) {
    float li[4];
    #pragma unroll
    for (int fn = 0; fn < 4; ++fn) li[fn] = LinvS[tw * 64 + fn * 16 + l16];
    #pragma unroll
    for (int fm = 0; fm < 4; ++fm)
      #pragma unroll
      for (int fn = 0; fn < 4; ++fn) {
        const int t = t0 + tw * 64 + fn * 16 + l16;
        B4 o;
        __bf16* op = &o.a0;
        #pragma unroll
        for (int r = 0; r < 4; ++r) {
          const float v = (oacc[fm][fn][r] +
              sm.om[tw][(fm * 16 + quad * 4 + r) * 64 + fn * 16 + l16]) * li[fn];
          op[r] = (__bf16)v;
        }
        *(B4*)(ob + ((size_t)t * BBATCH + b) * EE + h * HD + fm * 16 + quad * 4) = o;
      }
  }
}

// ---------------- avg_w body (r2 form) -----------------------------------
__device__ void avg_body(const __bf16* __restrict__ qb,
                         const __bf16* __restrict__ kb,
                         const float* __restrict__ linv_ws,
                         float* __restrict__ avg_out, int bx,
                         __bf16* Qs0, __bf16* Qs1,
                         __bf16* Ks0, __bf16* Ks1) {
  const int tid = threadIdx.x, lane = tid & 63, w = tid >> 6;
  const int wm = w >> 1, wn = w & 1;
  const int quad = lane >> 4, l16 = lane & 15;

  const int xcd = bx & 7, slot = bx >> 3;
  const int bti = xcd * 4 + (slot >> 4);
  const int s0 = (slot & 15) * 128;
  const int b = bti >> 4, t0 = (bti & 15) * 128;

  const __bf16* qt = qb + (((size_t)b * HN) * TT + t0) * HD;
  const __bf16* kt = kb + (((size_t)b * HN) * TT + s0) * HD;
  const float* lrow0 = linv_ws + ((size_t)b * HN) * TT + t0 + wm * 64;

  #pragma unroll
  for (int c = 0; c < 4; ++c) {
    stage8(qt, HD, Qs0, w * 32 + c * 8, lane);
    stage8(kt, HD, Ks0, w * 32 + c * 8, lane);
  }

  f32x4 aacc[4][4] = {};

  for (int h = 0; h < HN; ++h) {
    const int cur = h & 1;
    barrier_fence();
    if (h + 1 < HN) {
      const __bf16* qn = qt + (size_t)(h + 1) * TT * HD;
      const __bf16* kn = kt + (size_t)(h + 1) * TT * HD;
      __bf16* Qn = cur ? Qs0 : Qs1;
      __bf16* Kn = cur ? Ks0 : Ks1;
      #pragma unroll
      for (int c = 0; c < 4; ++c) {
        stage8(qn, HD, Qn, w * 32 + c * 8, lane);
        stage8(kn, HD, Kn, w * 32 + c * 8, lane);
      }
      asm volatile("s_waitcnt vmcnt(8)" ::: "memory");
    } else {
      asm volatile("s_waitcnt vmcnt(0)" ::: "memory");
    }
    barrier_fence();

    const __bf16* Qc = cur ? Qs1 : Qs0;
    const __bf16* Kc = cur ? Ks1 : Ks0;
    f32x4 sacc[4][4] = {};
    #pragma unroll
    for (int ks = 0; ks < 2; ++ks) {
      bfrag qf4[4], kf4[4];
      #pragma unroll
      for (int f = 0; f < 4; ++f)
        qf4[f] = *fragp(Qc, wm * 64 + f * 16 + l16, ks * 32 + quad * 8);
      #pragma unroll
      for (int f = 0; f < 4; ++f)
        kf4[f] = *fragp(Kc, wn * 64 + f * 16 + l16, ks * 32 + quad * 8);
      #pragma unroll
      for (int fm = 0; fm < 4; ++fm)
        #pragma unroll
        for (int fn = 0; fn < 4; ++fn)
          sacc[fm][fn] = mfma_bf16(qf4[fm], kf4[fn], sacc[fm][fn]);
    }

    const float* lr = lrow0 + (size_t)h * TT;
    f32x4 lvv[4];
    #pragma unroll
    for (int fm = 0; fm < 4; ++fm)
      lvv[fm] = *(const f32x4*)(lr + fm * 16 + quad * 4);

    #pragma unroll
    for (int fm = 0; fm < 4; ++fm)
      #pragma unroll
      for (int fn = 0; fn < 4; ++fn)
        #pragma unroll
        for (int r = 0; r < 4; ++r)
          aacc[fm][fn][r] += __builtin_amdgcn_exp2f(sacc[fm][fn][r]) * lvv[fm][r];
  }

  const float invh = 1.0f / (float)HN;
  #pragma unroll
  for (int fm = 0; fm < 4; ++fm)
    #pragma unroll
    for (int r = 0; r < 4; ++r) {
      const int t = t0 + wm * 64 + fm * 16 + quad * 4 + r;
      #pragma unroll
      for (int fn = 0; fn < 4; ++fn) {
        const int s = s0 + wn * 64 + fn * 16 + l16;
        avg_out[((size_t)b * TT + t) * TT + s] = aacc[fm][fn][r] * invh;
      }
    }
}

// ---------------- tail: avg_attn (blocks 0..511) + gemm_o (512..1023) ----
struct TailAvg { __bf16 Qs[2][128 * 64]; __bf16 Ks[2][128 * 64]; };  // 64KB
struct TailGo  { __bf16 As[2][64 * 64];  __bf16 Bs[2][128 * 64]; }; // 48KB
union TailSh { TailAvg a; TailGo g; };

__global__ __launch_bounds__(256, 2) void tail_fused(
    const __bf16* __restrict__ qb, const __bf16* __restrict__ kb,
    const float* __restrict__ linv_ws, float* __restrict__ avg_out,
    const __bf16* __restrict__ ob, const __bf16* __restrict__ wo,
    const float* __restrict__ bo, float* __restrict__ out) {
  __shared__ TailSh sh;
  const int bx = blockIdx.x;
  if (bx < 512) {
    avg_body(qb, kb, linv_ws, avg_out, bx,
             sh.a.Qs[0], sh.a.Qs[1], sh.a.Ks[0], sh.a.Ks[1]);
  } else {
    const int b2 = bx - 512;
    const int m = b2 & 63, n = b2 >> 6;
    gemm2<64>(ob, wo, bo, out, m * 64, n * 128,
              sh.g.As[0], sh.g.As[1], sh.g.Bs[0], sh.g.Bs[1]);
  }
}

extern "C" void kernel_launch(void* const* d_in, const int* in_sizes, int n_in,
                              void* d_out, int out_size, void* d_ws, size_t ws_size,
                              hipStream_t stream) {
  (void)in_sizes; (void)n_in; (void)out_size; (void)ws_size;
  const float* query = (const float*)d_in[0];
  const float* key   = (const float*)d_in[1];
  const float* value = (const float*)d_in[2];
  const float* Wq = (const float*)d_in[3];
  const float* bq = (const float*)d_in[4];
  const float* Wk = (const float*)d_in[5];
  const float* bk = (const float*)d_in[6];
  const float* Wv = (const float*)d_in[7];
  const float* bv = (const float*)d_in[8];
  const float* Wo = (const float*)d_in[9];
  const float* bo = (const float*)d_in[10];

  char* ws = (char*)d_ws;
  size_t off = 0;
  auto wsalloc = [&](size_t bytes) -> void* {
    void* p = ws + off;
    off += (bytes + 255) & ~(size_t)255;
    return p;
  };
  const size_t XE = (size_t)MM * EE;
  const size_t WE = (size_t)EE * EE;
  __bf16* qbuf = (__bf16*)wsalloc(XE * 2);
  __bf16* kbuf = (__bf16*)wsalloc(XE * 2);
  __bf16* vtbuf= (__bf16*)wsalloc(XE * 2);
  __bf16* obuf = (__bf16*)wsalloc(XE * 2);
  __bf16* wob  = (__bf16*)wsalloc(WE * 2);
  float* linv  = (float*)wsalloc((size_t)BBATCH * HN * TT * 4);

  gemm_qkv<<<dim3(768), 256, 0, stream>>>(query, key, value, Wq, Wk, Wv,
                                          bq, bk, bv, qbuf, kbuf, vtbuf,
                                          Wo, wob);

  attn_fwd<<<dim3(512), 256, 0, stream>>>(qbuf, kbuf, vtbuf, obuf, linv);

  float* avg_out = (float*)d_out + (size_t)TT * BBATCH * EE;
  tail_fused<<<dim3(1024), 256, 0, stream>>>(qbuf, kbuf, linv, avg_out,
                                             obuf, wob, bo, (float*)d_out);
}

// Round 6
// 243.574 us; speedup vs baseline: 1.9841x; 1.0117x over previous
//
#include <hip/hip_runtime.h>
#include <hip/hip_bf16.h>
#include <stdint.h>

#define HN 16      // heads
#define TT 2048    // seq len (T == S)
#define BBATCH 2
#define EE 1024
#define HD 64
#define MM 4096    // TT*BBATCH

// Q projection pre-scaled by 0.125*log2(e): exp2(q'.k) == exp(0.125*q.k).
#define SCALEQ 0.18033688011112042f

typedef __attribute__((ext_vector_type(8))) __bf16 bfrag;
typedef __attribute__((ext_vector_type(4))) float f32x4;
typedef __attribute__((ext_vector_type(4))) short s16x4;

struct alignas(8) B4 { __bf16 a0, a1, a2, a3; };

__device__ __forceinline__ void gll16(const void* g, void* lds) {
  __builtin_amdgcn_global_load_lds(
      (const __attribute__((address_space(1))) void*)g,
      (__attribute__((address_space(3))) void*)lds, 16, 0, 0);
}

__device__ __forceinline__ f32x4 mfma_bf16(bfrag a, bfrag b, f32x4 c) {
  return __builtin_amdgcn_mfma_f32_16x16x32_bf16(a, b, c, 0, 0, 0);
}

// ---- XOR-swizzled 64-elem-row LDS tiles (16B chunk c of row r at c^(r&7)) --
__device__ __forceinline__ const bfrag* fragp(const __bf16* base, int row, int e) {
  return (const bfrag*)(base + row * 64 + ((((e >> 3) ^ row) & 7) << 3));
}
__device__ __forceinline__ void stage8(const __bf16* grow0, int gstride,
                                       __bf16* tile, int r0, int lane) {
  const int rr = lane >> 3;
  const int cl = (lane & 7) ^ rr;
  gll16(grow0 + (size_t)(r0 + rr) * gstride + cl * 8, tile + r0 * 64);
}

// counted-vmcnt barrier (kept ONLY for attn/avg: measured win there in r2;
// measured LOSS for the GEMM structure -> GEMMs use plain __syncthreads)
__device__ __forceinline__ void barrier_fence() {
  __builtin_amdgcn_s_barrier();
  __builtin_amdgcn_sched_barrier(0);
}

// ---------------- fp32 -> bf16 conversion (7 tensors in one launch) -------
struct CvtArgs {
  const float* src[7];
  __bf16* dst[7];
  int n4[7];
};

__global__ __launch_bounds__(256) void cvt_all(CvtArgs a) {
  const int z = blockIdx.z;
  const int i = blockIdx.x * 256 + threadIdx.x;
  if (i < a.n4[z]) {
    float4 v = ((const float4*)a.src[z])[i];
    B4 o = {(__bf16)v.x, (__bf16)v.y, (__bf16)v.z, (__bf16)v.w};
    ((B4*)a.dst[z])[i] = o;
  }
}

// ---------------- QKV GEMM: r0 structure at 512 threads (8 waves) ---------
// 128x128 tile, BK=64, gll16 dbuf, ONE barrier/iter (r0-measured-best loop).
// 8 waves (2Mx4N), per-wave 64x32 output -> acc 32 VGPR. LDS 64KB -> 2
// blocks/CU, but 16 waves/CU (vs 8 at 256 thr): doubles the cross-wave
// overlap at the per-iter staging drain.
__global__ __launch_bounds__(512, 4) void gemm_qkv(
    const __bf16* __restrict__ xq, const __bf16* __restrict__ xk,
    const __bf16* __restrict__ xv, const __bf16* __restrict__ wq,
    const __bf16* __restrict__ wk, const __bf16* __restrict__ wv,
    const float* __restrict__ bq, const float* __restrict__ bk,
    const float* __restrict__ bv, __bf16* __restrict__ qo,
    __bf16* __restrict__ ko, __bf16* __restrict__ vo) {
  __shared__ __bf16 As[2][128 * 64];   // 32KB
  __shared__ __bf16 Bs[2][128 * 64];   // 32KB
  const int tid = threadIdx.x, lane = tid & 63, w = tid >> 6;   // w 0..7
  const int wm = w >> 2, wn = w & 3;
  const int quad = lane >> 4, l16 = lane & 15;

  // bx = m + 32*(n + 8*z): bx%8 == m%8 -> n-blocks sharing an A-tile on one XCD
  const int bx = blockIdx.x;
  const int m = bx & 31, n = (bx >> 5) & 7, z = bx >> 8;
  const __bf16 *X, *W;
  const float* bias;
  __bf16* out;
  int mode;
  float scale;
  if (z == 0)      { X = xq; W = wq; bias = bq; out = qo; mode = 0; scale = SCALEQ; }
  else if (z == 1) { X = xk; W = wk; bias = bk; out = ko; mode = 0; scale = 1.0f; }
  else             { X = xv; W = wv; bias = bv; out = vo; mode = 2; scale = 1.0f; }
  const int m0 = m * 128, n0 = n * 128;

  auto stageAB = [&](int buf, int k0) {
    __bf16* A = As[buf];
    __bf16* B = Bs[buf];
    #pragma unroll
    for (int c = 0; c < 2; ++c)
      stage8(X + (size_t)m0 * EE + k0, EE, A, w * 16 + c * 8, lane);
    #pragma unroll
    for (int c = 0; c < 2; ++c)
      stage8(W + (size_t)n0 * EE + k0, EE, B, w * 16 + c * 8, lane);
  };

  stageAB(0, 0);

  f32x4 acc[4][2] = {};

  for (int it = 0; it < 16; ++it) {
    const int cur = it & 1;
    __syncthreads();                 // buf[cur] staged; prior reads done
    if (it + 1 < 16) stageAB(1 - cur, (it + 1) * 64);

    const __bf16* A = As[cur];
    const __bf16* B = Bs[cur];
    #pragma unroll
    for (int ks = 0; ks < 2; ++ks) {
      bfrag a[4], b[2];
      #pragma unroll
      for (int f = 0; f < 4; ++f)
        a[f] = *fragp(A, wm * 64 + f * 16 + l16, ks * 32 + quad * 8);
      #pragma unroll
      for (int f = 0; f < 2; ++f)
        b[f] = *fragp(B, wn * 32 + f * 16 + l16, ks * 32 + quad * 8);
      #pragma unroll
      for (int fm = 0; fm < 4; ++fm)
        #pragma unroll
        for (int fn = 0; fn < 2; ++fn)
          acc[fm][fn] = mfma_bf16(a[fm], b[fn], acc[fm][fn]);
    }
  }

  float bvv[2];
  #pragma unroll
  for (int fn = 0; fn < 2; ++fn) bvv[fn] = bias[n0 + wn * 32 + fn * 16 + l16];

  #pragma unroll
  for (int fm = 0; fm < 4; ++fm) {
    #pragma unroll
    for (int r = 0; r < 4; ++r) {
      const int gm = m0 + wm * 64 + fm * 16 + quad * 4 + r;
      #pragma unroll
      for (int fn = 0; fn < 2; ++fn) {
        const int gn = n0 + wn * 32 + fn * 16 + l16;
        const float v = (acc[fm][fn][r] + bvv[fn]) * scale;
        if (mode == 0) {
          const int t = gm >> 1, bb = gm & 1, h = gn >> 6, d = gn & 63;
          out[(((size_t)(bb * HN + h)) * TT + t) * HD + d] = (__bf16)v;
        } else {
          const int s = gm >> 1, bb = gm & 1, h = gn >> 6, d = gn & 63;
          out[(((size_t)(bb * HN + h)) * HD + d) * TT + s] = (__bf16)v;
        }
      }
    }
  }
}

// ---------------- GEMM core (r0 plain-syncthreads form): tail gemm_o ------
template <int MT>
__device__ __forceinline__ void gemm2(const __bf16* __restrict__ X,
                                      const __bf16* __restrict__ W,
                                      const float* __restrict__ bias,
                                      float* __restrict__ out,
                                      int m0, int n0,
                                      __bf16* As0, __bf16* As1,
                                      __bf16* Bs0, __bf16* Bs1) {
  const int tid = threadIdx.x, lane = tid & 63, w = tid >> 6;
  const int wm = w >> 1, wn = w & 1;
  const int quad = lane >> 4, l16 = lane & 15;
  constexpr int FM = MT / 32;   // m-frags per wave

  auto stageAB = [&](int buf, int k0) {
    __bf16* A = buf ? As1 : As0;
    __bf16* B = buf ? Bs1 : Bs0;
    #pragma unroll
    for (int c = 0; c < FM; ++c)
      stage8(X + (size_t)m0 * EE + k0, EE, A, w * (MT / 4) + c * 8, lane);
    #pragma unroll
    for (int c = 0; c < 4; ++c)
      stage8(W + (size_t)n0 * EE + k0, EE, B, w * 32 + c * 8, lane);
  };

  stageAB(0, 0);

  f32x4 acc[FM][4] = {};

  for (int it = 0; it < EE / 64; ++it) {
    const int cur = it & 1;
    __syncthreads();                 // buf[cur] staged; prior reads done
    if (it + 1 < EE / 64) stageAB(1 - cur, (it + 1) * 64);

    const __bf16* A = cur ? As1 : As0;
    const __bf16* B = cur ? Bs1 : Bs0;
    #pragma unroll
    for (int ks = 0; ks < 2; ++ks) {
      bfrag a[FM], b[4];
      #pragma unroll
      for (int f = 0; f < FM; ++f)
        a[f] = *fragp(A, wm * (MT / 2) + f * 16 + l16, ks * 32 + quad * 8);
      #pragma unroll
      for (int f = 0; f < 4; ++f)
        b[f] = *fragp(B, wn * 64 + f * 16 + l16, ks * 32 + quad * 8);
      #pragma unroll
      for (int fm = 0; fm < FM; ++fm)
        #pragma unroll
        for (int fn = 0; fn < 4; ++fn)
          acc[fm][fn] = mfma_bf16(a[fm], b[fn], acc[fm][fn]);
    }
  }

  float bv[4];
  #pragma unroll
  for (int fn = 0; fn < 4; ++fn) bv[fn] = bias[n0 + wn * 64 + fn * 16 + l16];

  #pragma unroll
  for (int fm = 0; fm < FM; ++fm) {
    #pragma unroll
    for (int r = 0; r < 4; ++r) {
      const int gm = m0 + wm * (MT / 2) + fm * 16 + quad * 4 + r;
      #pragma unroll
      for (int fn = 0; fn < 4; ++fn) {
        const int gn = n0 + wn * 64 + fn * 16 + l16;
        out[(size_t)gm * EE + gn] = acc[fm][fn][r] + bv[fn];
      }
    }
  }
}

// ---------------- flash attention fwd: O (normalized) + linv (r2 form) ---
__global__ __launch_bounds__(256, 2) void attn_fwd(const __bf16* __restrict__ qb,
                                                   const __bf16* __restrict__ kb,
                                                   const __bf16* __restrict__ vtb,
                                                   __bf16* __restrict__ ob,
                                                   float* __restrict__ linv_ws) {
  union Sh {
    __bf16 kv[2][2][2][64 * 64];  // [pair][K=0/V=1][buf] 64KB
    float om[2][64 * 64];         // epilogue O-merge scratch (32KB, aliased)
  };
  __shared__ Sh sm;
  __shared__ float Lsum[2][128];
  __shared__ float LinvS[128];

  const int tid = threadIdx.x, lane = tid & 63, w = tid >> 6;
  const int p = w >> 1, tw = w & 1;
  const int quad = lane >> 4, l16 = lane & 15;

  const int bx = blockIdx.x;
  const int xcd = bx & 7, slot = bx >> 3;
  const int bhi = xcd * 4 + (slot >> 4);
  const int t0 = (slot & 15) * 128;
  const int b = bhi >> 4, h = bhi & 15;
  const size_t bh = (size_t)(b * HN + h);

  const __bf16* qbase = qb + (bh * TT + t0) * HD;
  const __bf16* kbase = kb + bh * TT * HD;
  const __bf16* vbase = vtb + bh * HD * TT;
  const int sBase = p * 1024;

  #pragma unroll
  for (int c = 0; c < 4; ++c) {
    stage8(kbase + (size_t)sBase * HD, HD, sm.kv[p][0][0], tw * 32 + c * 8, lane);
    stage8(vbase + sBase, TT, sm.kv[p][1][0], tw * 32 + c * 8, lane);
  }

  bfrag qf[4][2];
  #pragma unroll
  for (int fn = 0; fn < 4; ++fn)
    #pragma unroll
    for (int ks = 0; ks < 2; ++ks)
      qf[fn][ks] = *(const bfrag*)(qbase +
          (size_t)(tw * 64 + fn * 16 + l16) * HD + ks * 32 + quad * 8);

  bfrag ones;
  {
    union { short s[8]; bfrag v; } u;
    #pragma unroll
    for (int i = 0; i < 8; ++i) u.s[i] = 0x3F80;   // bf16 1.0
    ones = u.v;
  }

  f32x4 oacc[4][4] = {};   // [fm_d][fn_t] of O^T
  f32x4 lacc[4] = {};      // row sums via ones-MFMA

  for (int it = 0; it < 16; ++it) {
    const int cur = it & 1;
    barrier_fence();
    if (it + 1 < 16) {
      const int s1 = sBase + (it + 1) * 64;
      #pragma unroll
      for (int c = 0; c < 4; ++c) {
        stage8(kbase + (size_t)s1 * HD, HD, sm.kv[p][0][1 - cur], tw * 32 + c * 8, lane);
        stage8(vbase + s1, TT, sm.kv[p][1][1 - cur], tw * 32 + c * 8, lane);
      }
      asm volatile("s_waitcnt vmcnt(8)" ::: "memory");
    } else {
      asm volatile("s_waitcnt vmcnt(0)" ::: "memory");
    }
    barrier_fence();

    // ---- S^T[s][t] = K.Q
    f32x4 sacc[4][4] = {};
    #pragma unroll
    for (int ks = 0; ks < 2; ++ks) {
      bfrag kf[4];
      #pragma unroll
      for (int fm = 0; fm < 4; ++fm)
        kf[fm] = *fragp(sm.kv[p][0][cur], fm * 16 + l16, ks * 32 + quad * 8);
      #pragma unroll
      for (int fm = 0; fm < 4; ++fm)
        #pragma unroll
        for (int fn = 0; fn < 4; ++fn)
          sacc[fm][fn] = mfma_bf16(kf[fm], qf[fn][ks], sacc[fm][fn]);
    }

    // ---- exp2 in registers; pack into x32 B-operands
    union PB { __bf16 hh[8]; bfrag v; } pb[2][4];
    #pragma unroll
    for (int fm = 0; fm < 4; ++fm)
      #pragma unroll
      for (int fn = 0; fn < 4; ++fn) {
        const float p0 = __builtin_amdgcn_exp2f(sacc[fm][fn][0]);
        const float p1 = __builtin_amdgcn_exp2f(sacc[fm][fn][1]);
        const float p2 = __builtin_amdgcn_exp2f(sacc[fm][fn][2]);
        const float p3 = __builtin_amdgcn_exp2f(sacc[fm][fn][3]);
        const int hb = (fm & 1) * 4;
        pb[fm >> 1][fn].hh[hb + 0] = (__bf16)p0;
        pb[fm >> 1][fn].hh[hb + 1] = (__bf16)p1;
        pb[fm >> 1][fn].hh[hb + 2] = (__bf16)p2;
        pb[fm >> 1][fn].hh[hb + 3] = (__bf16)p3;
      }

    // ---- O^T += V^T.P^T ; l += 1.P^T on the MFMA pipe
    #pragma unroll
    for (int ks = 0; ks < 2; ++ks) {
      bfrag vf[4];
      #pragma unroll
      for (int fm = 0; fm < 4; ++fm) {
        const __bf16* base = sm.kv[p][1][cur] + (fm * 16 + l16) * 64;
        const int sw = l16 & 7, qh = quad >> 1, qo = (quad & 1) * 4;
        union VF { s16x4 q[2]; bfrag v; } u;
        u.q[0] = *(const s16x4*)(base + (((ks * 4 + qh) ^ sw) << 3) + qo);
        u.q[1] = *(const s16x4*)(base + (((ks * 4 + 2 + qh) ^ sw) << 3) + qo);
        vf[fm] = u.v;
      }
      #pragma unroll
      for (int fn = 0; fn < 4; ++fn)
        lacc[fn] = mfma_bf16(ones, pb[ks][fn].v, lacc[fn]);
      #pragma unroll
      for (int fm = 0; fm < 4; ++fm)
        #pragma unroll
        for (int fn = 0; fn < 4; ++fn)
          oacc[fm][fn] = mfma_bf16(vf[fm], pb[ks][fn].v, oacc[fm][fn]);
    }
  }

  if (quad == 0)
    #pragma unroll
    for (int fn = 0; fn < 4; ++fn)
      Lsum[p][tw * 64 + fn * 16 + l16] = lacc[fn][0];

  __syncthreads();   // Lsum visible; K/V reads done -> om may alias

  if (p == 1) {
    #pragma unroll
    for (int fm = 0; fm < 4; ++fm)
      #pragma unroll
      for (int fn = 0; fn < 4; ++fn)
        #pragma unroll
        for (int r = 0; r < 4; ++r)
          sm.om[tw][(fm * 16 + quad * 4 + r) * 64 + fn * 16 + l16] = oacc[fm][fn][r];
  }
  if (tid < 128) {
    const float linv = 1.0f / (Lsum[0][tid] + Lsum[1][tid]);
    LinvS[tid] = linv;
    linv_ws[bh * TT + t0 + tid] = linv;
  }
  __syncthreads();

  if (p == 0) {
    float li[4];
    #pragma unroll
    for (int fn = 0; fn < 4; ++fn) li[fn] = LinvS[tw * 64 + fn * 16 + l16];
    #pragma unroll
    for (int fm = 0; fm < 4; ++fm)
      #pragma unroll
      for (int fn = 0; fn < 4; ++fn) {
        const int t = t0 + tw * 64 + fn * 16 + l16;
        B4 o;
        __bf16* op = &o.a0;
        #pragma unroll
        for (int r = 0; r < 4; ++r) {
          const float v = (oacc[fm][fn][r] +
              sm.om[tw][(fm * 16 + quad * 4 + r) * 64 + fn * 16 + l16]) * li[fn];
          op[r] = (__bf16)v;
        }
        *(B4*)(ob + ((size_t)t * BBATCH + b) * EE + h * HD + fm * 16 + quad * 4) = o;
      }
  }
}

// ---------------- avg_w body (r2 form) -----------------------------------
__device__ void avg_body(const __bf16* __restrict__ qb,
                         const __bf16* __restrict__ kb,
                         const float* __restrict__ linv_ws,
                         float* __restrict__ avg_out, int bx,
                         __bf16* Qs0, __bf16* Qs1,
                         __bf16* Ks0, __bf16* Ks1) {
  const int tid = threadIdx.x, lane = tid & 63, w = tid >> 6;
  const int wm = w >> 1, wn = w & 1;
  const int quad = lane >> 4, l16 = lane & 15;

  const int xcd = bx & 7, slot = bx >> 3;
  const int bti = xcd * 4 + (slot >> 4);
  const int s0 = (slot & 15) * 128;
  const int b = bti >> 4, t0 = (bti & 15) * 128;

  const __bf16* qt = qb + (((size_t)b * HN) * TT + t0) * HD;
  const __bf16* kt = kb + (((size_t)b * HN) * TT + s0) * HD;
  const float* lrow0 = linv_ws + ((size_t)b * HN) * TT + t0 + wm * 64;

  #pragma unroll
  for (int c = 0; c < 4; ++c) {
    stage8(qt, HD, Qs0, w * 32 + c * 8, lane);
    stage8(kt, HD, Ks0, w * 32 + c * 8, lane);
  }

  f32x4 aacc[4][4] = {};

  for (int h = 0; h < HN; ++h) {
    const int cur = h & 1;
    barrier_fence();
    if (h + 1 < HN) {
      const __bf16* qn = qt + (size_t)(h + 1) * TT * HD;
      const __bf16* kn = kt + (size_t)(h + 1) * TT * HD;
      __bf16* Qn = cur ? Qs0 : Qs1;
      __bf16* Kn = cur ? Ks0 : Ks1;
      #pragma unroll
      for (int c = 0; c < 4; ++c) {
        stage8(qn, HD, Qn, w * 32 + c * 8, lane);
        stage8(kn, HD, Kn, w * 32 + c * 8, lane);
      }
      asm volatile("s_waitcnt vmcnt(8)" ::: "memory");
    } else {
      asm volatile("s_waitcnt vmcnt(0)" ::: "memory");
    }
    barrier_fence();

    const __bf16* Qc = cur ? Qs1 : Qs0;
    const __bf16* Kc = cur ? Ks1 : Ks0;
    f32x4 sacc[4][4] = {};
    #pragma unroll
    for (int ks = 0; ks < 2; ++ks) {
      bfrag qf4[4], kf4[4];
      #pragma unroll
      for (int f = 0; f < 4; ++f)
        qf4[f] = *fragp(Qc, wm * 64 + f * 16 + l16, ks * 32 + quad * 8);
      #pragma unroll
      for (int f = 0; f < 4; ++f)
        kf4[f] = *fragp(Kc, wn * 64 + f * 16 + l16, ks * 32 + quad * 8);
      #pragma unroll
      for (int fm = 0; fm < 4; ++fm)
        #pragma unroll
        for (int fn = 0; fn < 4; ++fn)
          sacc[fm][fn] = mfma_bf16(qf4[fm], kf4[fn], sacc[fm][fn]);
    }

    const float* lr = lrow0 + (size_t)h * TT;
    f32x4 lvv[4];
    #pragma unroll
    for (int fm = 0; fm < 4; ++fm)
      lvv[fm] = *(const f32x4*)(lr + fm * 16 + quad * 4);

    #pragma unroll
    for (int fm = 0; fm < 4; ++fm)
      #pragma unroll
      for (int fn = 0; fn < 4; ++fn)
        #pragma unroll
        for (int r = 0; r < 4; ++r)
          aacc[fm][fn][r] += __builtin_amdgcn_exp2f(sacc[fm][fn][r]) * lvv[fm][r];
  }

  const float invh = 1.0f / (float)HN;
  #pragma unroll
  for (int fm = 0; fm < 4; ++fm)
    #pragma unroll
    for (int r = 0; r < 4; ++r) {
      const int t = t0 + wm * 64 + fm * 16 + quad * 4 + r;
      #pragma unroll
      for (int fn = 0; fn < 4; ++fn) {
        const int s = s0 + wn * 64 + fn * 16 + l16;
        avg_out[((size_t)b * TT + t) * TT + s] = aacc[fm][fn][r] * invh;
      }
    }
}

// ---------------- tail: avg_attn (blocks 0..511) + gemm_o (512..1023) ----
struct TailAvg { __bf16 Qs[2][128 * 64]; __bf16 Ks[2][128 * 64]; };  // 64KB
struct TailGo  { __bf16 As[2][64 * 64];  __bf16 Bs[2][128 * 64]; }; // 48KB
union TailSh { TailAvg a; TailGo g; };

__global__ __launch_bounds__(256, 2) void tail_fused(
    const __bf16* __restrict__ qb, const __bf16* __restrict__ kb,
    const float* __restrict__ linv_ws, float* __restrict__ avg_out,
    const __bf16* __restrict__ ob, const __bf16* __restrict__ wo,
    const float* __restrict__ bo, float* __restrict__ out) {
  __shared__ TailSh sh;
  const int bx = blockIdx.x;
  if (bx < 512) {
    avg_body(qb, kb, linv_ws, avg_out, bx,
             sh.a.Qs[0], sh.a.Qs[1], sh.a.Ks[0], sh.a.Ks[1]);
  } else {
    const int b2 = bx - 512;
    const int m = b2 & 63, n = b2 >> 6;
    gemm2<64>(ob, wo, bo, out, m * 64, n * 128,
              sh.g.As[0], sh.g.As[1], sh.g.Bs[0], sh.g.Bs[1]);
  }
}

extern "C" void kernel_launch(void* const* d_in, const int* in_sizes, int n_in,
                              void* d_out, int out_size, void* d_ws, size_t ws_size,
                              hipStream_t stream) {
  (void)in_sizes; (void)n_in; (void)out_size; (void)ws_size;
  const float* query = (const float*)d_in[0];
  const float* key   = (const float*)d_in[1];
  const float* value = (const float*)d_in[2];
  const float* Wq = (const float*)d_in[3];
  const float* bq = (const float*)d_in[4];
  const float* Wk = (const float*)d_in[5];
  const float* bk = (const float*)d_in[6];
  const float* Wv = (const float*)d_in[7];
  const float* bv = (const float*)d_in[8];
  const float* Wo = (const float*)d_in[9];
  const float* bo = (const float*)d_in[10];

  char* ws = (char*)d_ws;
  size_t off = 0;
  auto wsalloc = [&](size_t bytes) -> void* {
    void* p = ws + off;
    off += (bytes + 255) & ~(size_t)255;
    return p;
  };
  const size_t XE = (size_t)MM * EE;
  const size_t WE = (size_t)EE * EE;
  __bf16* xq   = (__bf16*)wsalloc(XE * 2);
  __bf16* xk   = (__bf16*)wsalloc(XE * 2);
  __bf16* xv   = (__bf16*)wsalloc(XE * 2);
  __bf16* wqb  = (__bf16*)wsalloc(WE * 2);
  __bf16* wkb  = (__bf16*)wsalloc(WE * 2);
  __bf16* wvb  = (__bf16*)wsalloc(WE * 2);
  __bf16* wob  = (__bf16*)wsalloc(WE * 2);
  __bf16* qbuf = (__bf16*)wsalloc(XE * 2);
  __bf16* kbuf = (__bf16*)wsalloc(XE * 2);
  __bf16* vtbuf= (__bf16*)wsalloc(XE * 2);
  __bf16* obuf = (__bf16*)wsalloc(XE * 2);
  float* linv  = (float*)wsalloc((size_t)BBATCH * HN * TT * 4);

  CvtArgs ca;
  ca.src[0] = query; ca.dst[0] = xq;  ca.n4[0] = (int)(XE / 4);
  ca.src[1] = key;   ca.dst[1] = xk;  ca.n4[1] = (int)(XE / 4);
  ca.src[2] = value; ca.dst[2] = xv;  ca.n4[2] = (int)(XE / 4);
  ca.src[3] = Wq;    ca.dst[3] = wqb; ca.n4[3] = (int)(WE / 4);
  ca.src[4] = Wk;    ca.dst[4] = wkb; ca.n4[4] = (int)(WE / 4);
  ca.src[5] = Wv;    ca.dst[5] = wvb; ca.n4[5] = (int)(WE / 4);
  ca.src[6] = Wo;    ca.dst[6] = wob; ca.n4[6] = (int)(WE / 4);
  cvt_all<<<dim3(4096, 1, 7), 256, 0, stream>>>(ca);

  gemm_qkv<<<dim3(768), 512, 0, stream>>>(xq, xk, xv, wqb, wkb, wvb,
                                          bq, bk, bv, qbuf, kbuf, vtbuf);

  attn_fwd<<<dim3(512), 256, 0, stream>>>(qbuf, kbuf, vtbuf, obuf, linv);

  float* avg_out = (float*)d_out + (size_t)TT * BBATCH * EE;
  tail_fused<<<dim3(1024), 256, 0, stream>>>(qbuf, kbuf, linv, avg_out,
                                             obuf, wob, bo, (float*)d_out);
}